// Round 4
// baseline (1363.294 us; speedup 1.0000x reference)
//
#include <hip/hip_runtime.h>
#include <hip/hip_bf16.h>

// Problem constants
#define N_POS 480000      // B*T*V = 64*300*25
#define NB    64
#define NT    300
#define NV    25
#define NCC   100
#define NTL   9
#define NL    292         // T - TL + 1

// Workspace float offsets
#define WS_XSUM   0       // 3
#define WS_XSS    3       // 6 (m00,m01,m02,m11,m12,m22)
#define WS_SC0    12      // 64
#define WS_SH0    76      // 64
#define WS_Z1SUM  140     // 128
#define WS_Z1SQ   268     // 128
#define WS_SC1    396     // 128
#define WS_SH1    524     // 128
#define WS_Z2SUM  652
#define WS_Z2SQ   653
#define WS_SC2    654
#define WS_SH2    655
#define WS_LOSS   656
#define WS_PAN    657
#define WS_REG    658
#define WS_SW     672     // 2500 = sum_l weight^2 (100x25)
#define WS_HM     3172    // 1600 (B*V t-means)
#define WS_Z2     4800    // 480000 (b,t,v)
#define WS_XS     484800  // 480000 (b,v,t)
#define WS_CM     964800  // 4,000,000 (b,c,i,j)
#define WS_P      4964800 // bf16 p buffer starts here

__device__ __forceinline__ float waveRed(float v) {
    #pragma unroll
    for (int off = 32; off > 0; off >>= 1) v += __shfl_down(v, off);
    return v;
}

// ---------------- Pass A: x channel stats ----------------
__global__ void k_xstats(const float* __restrict__ x, float* __restrict__ ws) {
    int tid = blockIdx.x * blockDim.x + threadIdx.x;
    int nth = gridDim.x * blockDim.x;
    float a0=0,a1=0,a2=0,m00=0,m01=0,m02=0,m11=0,m12=0,m22=0;
    for (int p = tid; p < N_POS; p += nth) {
        int b = p / 7500; int rem = p - b * 7500;
        const float* xb = x + b * 22500 + rem;
        float x0 = xb[0], x1 = xb[7500], x2 = xb[15000];
        a0+=x0; a1+=x1; a2+=x2;
        m00+=x0*x0; m01+=x0*x1; m02+=x0*x2; m11+=x1*x1; m12+=x1*x2; m22+=x2*x2;
    }
    a0=waveRed(a0); a1=waveRed(a1); a2=waveRed(a2);
    m00=waveRed(m00); m01=waveRed(m01); m02=waveRed(m02);
    m11=waveRed(m11); m12=waveRed(m12); m22=waveRed(m22);
    if ((threadIdx.x & 63) == 0) {
        atomicAdd(&ws[WS_XSUM+0],a0); atomicAdd(&ws[WS_XSUM+1],a1); atomicAdd(&ws[WS_XSUM+2],a2);
        atomicAdd(&ws[WS_XSS+0],m00); atomicAdd(&ws[WS_XSS+1],m01); atomicAdd(&ws[WS_XSS+2],m02);
        atomicAdd(&ws[WS_XSS+3],m11); atomicAdd(&ws[WS_XSS+4],m12); atomicAdd(&ws[WS_XSS+5],m22);
    }
}

// ---------------- sw[c,m] = sum_l weight[c,m,l]^2 ----------------
__global__ void k_prepw(const float* __restrict__ weight, float* __restrict__ ws) {
    int idx = blockIdx.x * blockDim.x + threadIdx.x;
    if (idx < 2500) {
        float s = 0;
        #pragma unroll
        for (int l = 0; l < NTL; l++) { float w = weight[idx*NTL + l]; s += w*w; }
        ws[WS_SW + idx] = s;
    }
}

// ---------------- BN0 affine from x moments (exact linearity) ----------------
__global__ void k_prep0(const float* __restrict__ w, const float* __restrict__ bb,
                        const float* __restrict__ g, const float* __restrict__ bt,
                        float* __restrict__ ws) {
    int o = threadIdx.x; // 64
    float inv = 1.0f / (float)N_POS;
    float mx0 = ws[WS_XSUM+0]*inv, mx1 = ws[WS_XSUM+1]*inv, mx2 = ws[WS_XSUM+2]*inv;
    float C00 = ws[WS_XSS+0]*inv - mx0*mx0;
    float C01 = ws[WS_XSS+1]*inv - mx0*mx1;
    float C02 = ws[WS_XSS+2]*inv - mx0*mx2;
    float C11 = ws[WS_XSS+3]*inv - mx1*mx1;
    float C12 = ws[WS_XSS+4]*inv - mx1*mx2;
    float C22 = ws[WS_XSS+5]*inv - mx2*mx2;
    float w0 = w[o*3], w1 = w[o*3+1], w2 = w[o*3+2];
    float mu  = w0*mx0 + w1*mx1 + w2*mx2 + bb[o];
    float var = w0*w0*C00 + w1*w1*C11 + w2*w2*C22
              + 2.f*(w0*w1*C01 + w0*w2*C02 + w1*w2*C12);
    float sc = g[o] / sqrtf(var + 1e-5f);
    ws[WS_SC0+o] = sc;
    ws[WS_SH0+o] = bt[o] - sc*mu;
}

// ---------------- z1 = fb1(relu(bn0(fb0(x)))) stats ----------------
__global__ __launch_bounds__(256) void k_z1stats(
        const float* __restrict__ x,
        const float* __restrict__ w0g, const float* __restrict__ b0g,
        const float* __restrict__ w1g, const float* __restrict__ b1g,
        float* __restrict__ ws) {
    __shared__ float s_sum[128], s_sq[128];
    int tid = threadIdx.x;
    if (tid < 128) { s_sum[tid] = 0.f; s_sq[tid] = 0.f; }
    __syncthreads();
    int p = blockIdx.x * 256 + tid;
    int b = p / 7500; int rem = p - b * 7500;
    const float* xb = x + b * 22500 + rem;
    float x0 = xb[0], x1 = xb[7500], x2 = xb[15000];
    float h0[64];
    #pragma unroll
    for (int o = 0; o < 64; o++) {
        float z = b0g[o] + w0g[o*3]*x0 + w0g[o*3+1]*x1 + w0g[o*3+2]*x2;
        h0[o] = fmaxf(ws[WS_SC0+o]*z + ws[WS_SH0+o], 0.f);
    }
    for (int o = 0; o < 128; o++) {
        float a = b1g[o];
        const float* wr = w1g + o*64;
        #pragma unroll
        for (int c = 0; c < 64; c++) a += wr[c]*h0[c];
        float a2 = a*a;
        a = waveRed(a); a2 = waveRed(a2);
        if ((tid & 63) == 0) { atomicAdd(&s_sum[o], a); atomicAdd(&s_sq[o], a2); }
    }
    __syncthreads();
    if (tid < 128) {
        atomicAdd(&ws[WS_Z1SUM+tid], s_sum[tid]);
        atomicAdd(&ws[WS_Z1SQ+tid],  s_sq[tid]);
    }
}

__global__ void k_prep1(const float* __restrict__ g, const float* __restrict__ bt,
                        float* __restrict__ ws) {
    int o = threadIdx.x; // 128
    float inv = 1.0f / (float)N_POS;
    float m = ws[WS_Z1SUM+o]*inv;
    float v = ws[WS_Z1SQ+o]*inv - m*m;
    float sc = g[o] / sqrtf(v + 1e-5f);
    ws[WS_SC1+o] = sc;
    ws[WS_SH1+o] = bt[o] - sc*m;
}

// ---------------- z2 = fb2(relu(bn1(z1))) ; store z2, stats ----------------
__global__ __launch_bounds__(256) void k_z2(
        const float* __restrict__ x,
        const float* __restrict__ w0g, const float* __restrict__ b0g,
        const float* __restrict__ w1g, const float* __restrict__ b1g,
        const float* __restrict__ w2g, const float* __restrict__ b2g,
        float* __restrict__ ws) {
    __shared__ float s_a, s_a2;
    int tid = threadIdx.x;
    if (tid == 0) { s_a = 0.f; s_a2 = 0.f; }
    __syncthreads();
    int p = blockIdx.x * 256 + tid;
    int b = p / 7500; int rem = p - b * 7500;
    const float* xb = x + b * 22500 + rem;
    float x0 = xb[0], x1 = xb[7500], x2 = xb[15000];
    float h0[64];
    #pragma unroll
    for (int o = 0; o < 64; o++) {
        float z = b0g[o] + w0g[o*3]*x0 + w0g[o*3+1]*x1 + w0g[o*3+2]*x2;
        h0[o] = fmaxf(ws[WS_SC0+o]*z + ws[WS_SH0+o], 0.f);
    }
    float z2 = b2g[0];
    for (int o = 0; o < 128; o++) {
        float a = b1g[o];
        const float* wr = w1g + o*64;
        #pragma unroll
        for (int c = 0; c < 64; c++) a += wr[c]*h0[c];
        float h1 = fmaxf(ws[WS_SC1+o]*a + ws[WS_SH1+o], 0.f);
        z2 += w2g[o]*h1;
    }
    ws[WS_Z2 + p] = z2;
    float a = waveRed(z2), a2 = waveRed(z2*z2);
    if ((tid & 63) == 0) { atomicAdd(&s_a, a); atomicAdd(&s_a2, a2); }
    __syncthreads();
    if (tid == 0) { atomicAdd(&ws[WS_Z2SUM], s_a); atomicAdd(&ws[WS_Z2SQ], s_a2); }
}

__global__ void k_prep2(const float* __restrict__ g, const float* __restrict__ bt,
                        float* __restrict__ ws) {
    float inv = 1.0f / (float)N_POS;
    float m = ws[WS_Z2SUM]*inv;
    float v = ws[WS_Z2SQ]*inv - m*m;
    float sc = g[0] / sqrtf(v + 1e-5f);
    ws[WS_SC2] = sc;
    ws[WS_SH2] = bt[0] - sc*m;
}

// ---------------- x_series (b,v,t) + per-(b,v) t-mean ----------------
__global__ void k_xs(float* __restrict__ ws) {
    __shared__ float red[128];
    int bid = blockIdx.x;       // b*25+v
    int b = bid / 25, v = bid - b*25;
    float sc = ws[WS_SC2], sh = ws[WS_SH2];
    float local = 0.f;
    for (int t = threadIdx.x; t < NT; t += 128) {
        float val = fmaxf(sc * ws[WS_Z2 + b*7500 + t*25 + v] + sh, 0.f);
        ws[WS_XS + (size_t)bid*NT + t] = val;
        local += val;
    }
    red[threadIdx.x] = local;
    __syncthreads();
    for (int s = 64; s > 0; s >>= 1) {
        if (threadIdx.x < s) red[threadIdx.x] += red[threadIdx.x + s];
        __syncthreads();
    }
    if (threadIdx.x == 0) ws[WS_HM + bid] = red[0] * (1.f/300.f);
}

// ---------------- cm[b,c,i,j] = tanh(x1[b,c,i]-x2[b,c,j]) ----------------
__global__ void k_cm(const float* __restrict__ c1w, const float* __restrict__ c1b,
                     const float* __restrict__ c2w, const float* __restrict__ c2b,
                     float* __restrict__ ws) {
    __shared__ float s_hm[25];
    int bid = blockIdx.x;       // b*100+c
    int b = bid / 100, c = bid - b*100;
    if (threadIdx.x < 25) s_hm[threadIdx.x] = ws[WS_HM + b*25 + threadIdx.x];
    float a1 = c1w[c], d1 = c1b[c], a2 = c2w[c], d2 = c2b[c];
    __syncthreads();
    for (int idx = threadIdx.x; idx < 625; idx += 256) {
        int i = idx / 25, j = idx - i*25;
        ws[WS_CM + (size_t)bid*625 + idx] = tanhf(a1*s_hm[i] + d1 - a2*s_hm[j] - d2);
    }
}

// ---------------- GCs ----------------
__global__ void k_gcs(const float* __restrict__ ws, float* __restrict__ out) {
    int gid = blockIdx.x * 256 + threadIdx.x;
    if (gid < 40000) {
        int b = gid / 625; int rem = gid - b*625; int m = rem % 25;
        float acc = 0.f;
        for (int c = 0; c < 100; c++) {
            float v = ws[WS_CM + ((size_t)(b*100+c))*625 + rem];
            acc += v*v*ws[WS_SW + c*25 + m];
        }
        out[gid] = sqrtf(acc);
    }
}

// ---------------- panelty ----------------
__global__ void k_pan(float* __restrict__ ws) {
    __shared__ float s_colsq[25];
    __shared__ float s_n1, s_r;
    int tid = threadIdx.x;
    int b = blockIdx.x;
    if (tid < 25) s_colsq[tid] = 0.f;
    if (tid == 0) { s_n1 = 0.f; s_r = 0.f; }
    __syncthreads();
    float ln1 = 0.f;
    for (int idx = tid; idx < 625; idx += 256) {
        int j = idx % 25;
        float sq = 0.f;
        for (int c = 0; c < 100; c++) {
            float v = ws[WS_CM + ((size_t)(b*100+c))*625 + idx];
            sq += v*v;
        }
        ln1 += sqrtf(sq);
        atomicAdd(&s_colsq[j], sq);
    }
    ln1 = waveRed(ln1);
    if ((tid & 63) == 0) atomicAdd(&s_n1, ln1);
    __syncthreads();
    if (tid < 25) atomicAdd(&s_r, sqrtf(s_colsq[tid]));
    __syncthreads();
    if (tid == 0) atomicAdd(&ws[WS_PAN], s_n1 + s_r);
}

// ---------------- regularize ----------------
__global__ void k_reg(const float* __restrict__ f0w, const float* __restrict__ f1w,
                      const float* __restrict__ f2w, float* __restrict__ ws) {
    int tid = blockIdx.x * blockDim.x + threadIdx.x;
    int nth = gridDim.x * blockDim.x;
    float a = 0.f;
    for (int i = tid; i < 275250; i += nth) {
        float w;
        if (i < 250000) w = f0w[i];
        else if (i < 275000) w = f1w[i - 250000];
        else w = f2w[i - 275000];
        a += w*w;
    }
    a = waveRed(a);
    if ((threadIdx.x & 63) == 0) atomicAdd(&ws[WS_REG], a);
}

// ---------------- Fc + p per (b,c), fused in LDS ----------------
__global__ __launch_bounds__(256) void k_fcp(
        const float* __restrict__ weight, const float* __restrict__ wnorm,
        __hip_bfloat16* __restrict__ pbuf, const float* __restrict__ ws, int b_base) {
    __shared__ float s_xs[7500];
    __shared__ float s_fc[25*NL];   // 7300
    __shared__ float s_wn[225];
    __shared__ float s_cm[625];
    int tid = threadIdx.x;
    int bid = blockIdx.x;
    int bl = bid / 100, c = bid - bl*100;
    int b = b_base + bl;
    for (int i = tid; i < 225; i += 256) s_wn[i] = weight[c*225 + i] / wnorm[i];
    for (int i = tid; i < 7500; i += 256) s_xs[i] = ws[WS_XS + (size_t)b*7500 + i];
    for (int i = tid; i < 625; i += 256) s_cm[i] = ws[WS_CM + ((size_t)(b*100+c))*625 + i];
    __syncthreads();
    for (int i = tid; i < 25*NL; i += 256) {
        int v = i / NL, t = i - v*NL;
        float f = 0.f;
        #pragma unroll
        for (int l = 0; l < NTL; l++) f += s_xs[v*NT + t + l] * s_wn[v*NTL + l];
        s_fc[i] = f;
    }
    __syncthreads();
    for (int i = tid; i < 25*NL; i += 256) {
        int ii = i / NL, t = i - ii*NL;
        float a = 0.f;
        #pragma unroll
        for (int v = 0; v < 25; v++) a += s_cm[v*25 + ii] * s_fc[v*NL + t];
        pbuf[((size_t)((bl*25 + ii)*100 + c))*NL + t] = __float2bfloat16(a);
    }
}

// ---------------- group MLP f0/f1/f2 + loss ----------------
__global__ __launch_bounds__(256) void k_mlp(
        const __hip_bfloat16* __restrict__ pbuf,
        const float* __restrict__ f0w, const float* __restrict__ f0b,
        const float* __restrict__ f1w, const float* __restrict__ f1b,
        const float* __restrict__ f2w, const float* __restrict__ f2b,
        float* __restrict__ ws, int b_base) {
    __shared__ float s_w1t[1000];   // [o][o2]
    __shared__ float s_loss;
    int tid = threadIdx.x;
    int bid = blockIdx.x;
    int bl = bid / 25, g = bid - bl*25;
    int b = b_base + bl;
    for (int i = tid; i < 1000; i += 256) {
        int o = i / 10, o2 = i - o*10;
        s_w1t[i] = f1w[g*1000 + o2*100 + o];
    }
    if (tid == 0) s_loss = 0.f;
    __syncthreads();
    const __hip_bfloat16* pg = pbuf + ((size_t)(bl*25 + g))*100*NL;
    const float* w0 = f0w + g*10000;
    const float* b0 = f0b + g*100;
    const float* b1 = f1b + g*10;
    const float* w2 = f2w + g*10;
    float b2 = f2b[g];
    float local = 0.f;
    for (int t = tid; t < NL; t += 256) {
        float pr[100];
        #pragma unroll
        for (int cc = 0; cc < 100; cc++) pr[cc] = __bfloat162float(pg[(size_t)cc*NL + t]);
        float acc2[10];
        #pragma unroll
        for (int o2 = 0; o2 < 10; o2++) acc2[o2] = b1[o2];
        for (int o = 0; o < 100; o++) {
            float a = b0[o];
            const float* wr = w0 + o*100;
            #pragma unroll
            for (int cc = 0; cc < 100; cc++) a += wr[cc]*pr[cc];
            a = fmaxf(a, 0.f);
            #pragma unroll
            for (int o2 = 0; o2 < 10; o2++) acc2[o2] += s_w1t[o*10 + o2]*a;
        }
        float z3 = b2;
        #pragma unroll
        for (int o2 = 0; o2 < 10; o2++) z3 += w2[o2]*fmaxf(acc2[o2], 0.f);
        z3 = fmaxf(z3, 0.f);
        if (t < NL-1) {
            float d = ws[WS_XS + ((size_t)(b*25 + g))*NT + t + NTL] - z3;
            local += d*d;
        }
    }
    local = waveRed(local);
    if ((tid & 63) == 0) atomicAdd(&s_loss, local);
    __syncthreads();
    if (tid == 0) atomicAdd(&ws[WS_LOSS], s_loss);
}

// ---------------- final scalars ----------------
__global__ void k_final(float* __restrict__ out, const float* __restrict__ ws) {
    out[40000] = ws[WS_LOSS] * (1.f / 465600.f);
    out[40001] = 1e-4f * ws[WS_PAN];
    out[40002] = 1e-4f * ws[WS_REG];
}

extern "C" void kernel_launch(void* const* d_in, const int* in_sizes, int n_in,
                              void* d_out, int out_size, void* d_ws, size_t ws_size,
                              hipStream_t stream) {
    const float* x      = (const float*)d_in[0];
    const float* weight = (const float*)d_in[1];
    const float* wnorm  = (const float*)d_in[2];
    const float* fb0_w  = (const float*)d_in[3];
    const float* fb0_b  = (const float*)d_in[4];
    const float* bn0_g  = (const float*)d_in[5];
    const float* bn0_b  = (const float*)d_in[6];
    const float* fb1_w  = (const float*)d_in[7];
    const float* fb1_b  = (const float*)d_in[8];
    const float* bn1_g  = (const float*)d_in[9];
    const float* bn1_b  = (const float*)d_in[10];
    const float* fb2_w  = (const float*)d_in[11];
    const float* fb2_b  = (const float*)d_in[12];
    const float* bn2_g  = (const float*)d_in[13];
    const float* bn2_b  = (const float*)d_in[14];
    const float* c1_w   = (const float*)d_in[15];
    const float* c1_b   = (const float*)d_in[16];
    const float* c2_w   = (const float*)d_in[17];
    const float* c2_b   = (const float*)d_in[18];
    const float* f0_w   = (const float*)d_in[19];
    const float* f0_b   = (const float*)d_in[20];
    const float* f1_w   = (const float*)d_in[21];
    const float* f1_b   = (const float*)d_in[22];
    const float* f2_w   = (const float*)d_in[23];
    const float* f2_b   = (const float*)d_in[24];

    float* ws  = (float*)d_ws;
    float* out = (float*)d_out;
    __hip_bfloat16* pbuf = (__hip_bfloat16*)(ws + WS_P);

    // zero accumulators (floats 0..659)
    hipMemsetAsync(d_ws, 0, 2640, stream);

    k_xstats<<<512, 256, 0, stream>>>(x, ws);
    k_prepw<<<10, 256, 0, stream>>>(weight, ws);
    k_prep0<<<1, 64, 0, stream>>>(fb0_w, fb0_b, bn0_g, bn0_b, ws);
    k_z1stats<<<1875, 256, 0, stream>>>(x, fb0_w, fb0_b, fb1_w, fb1_b, ws);
    k_prep1<<<1, 128, 0, stream>>>(bn1_g, bn1_b, ws);
    k_z2<<<1875, 256, 0, stream>>>(x, fb0_w, fb0_b, fb1_w, fb1_b, fb2_w, fb2_b, ws);
    k_prep2<<<1, 1, 0, stream>>>(bn2_g, bn2_b, ws);
    k_xs<<<1600, 128, 0, stream>>>(ws);
    k_cm<<<6400, 256, 0, stream>>>(c1_w, c1_b, c2_w, c2_b, ws);
    k_gcs<<<157, 256, 0, stream>>>(ws, out);
    k_pan<<<64, 256, 0, stream>>>(ws);
    k_reg<<<256, 256, 0, stream>>>(f0_w, f1_w, f2_w, ws);

    // Adaptive b-chunking for the bf16 p buffer (deterministic in ws_size ->
    // identical work every call; graph-capture safe).
    const size_t p_bytes_per_b = (size_t)25*100*NL*sizeof(__hip_bfloat16); // 1.46 MB
    size_t fixed_bytes = (size_t)WS_P * sizeof(float);
    size_t avail = ws_size > fixed_bytes ? ws_size - fixed_bytes : 0;
    int bs = (int)(avail / p_bytes_per_b);
    if (bs > 64) bs = 64;
    if (bs < 1)  bs = 1;   // requires ~21.3 MB ws minimum
    for (int b0 = 0; b0 < 64; b0 += bs) {
        int nb = (64 - b0) < bs ? (64 - b0) : bs;
        k_fcp<<<nb*100, 256, 0, stream>>>(weight, wnorm, pbuf, ws, b0);
        k_mlp<<<nb*25, 256, 0, stream>>>(pbuf, f0_w, f0_b, f1_w, f1_b, f2_w, f2_b, ws, b0);
    }
    k_final<<<1, 1, 0, stream>>>(out, ws);
}

// Round 5
// 1126.499 us; speedup vs baseline: 1.2102x; 1.2102x over previous
//
#include <hip/hip_runtime.h>
#include <hip/hip_bf16.h>

// Problem constants
#define N_POS 480000      // B*T*V = 64*300*25
#define NB    64
#define NT    300
#define NV    25
#define NCC   100
#define NTL   9
#define NL    292         // T - TL + 1

// Workspace float offsets
#define WS_XSUM   0       // 3
#define WS_XSS    3       // 6 (m00,m01,m02,m11,m12,m22)
#define WS_Z1SUM  140     // 128 (atomic acc)
#define WS_Z1SQ   268     // 128 (atomic acc)
#define WS_SC1    396     // 128
#define WS_SH1    524     // 128
#define WS_Z2SUM  652
#define WS_Z2SQ   653
#define WS_SC2    654
#define WS_SH2    655
#define WS_LOSS   656
#define WS_PAN    657
#define WS_REG    658
#define WS_WA     768     // 256: packed (sc*w0, sc*w1, sc*w2, ba) per ch
#define WS_W1T    1024    // 8192: W1 transposed [c][o]
#define WS_SW     9216    // 2500 = sum_l weight^2 (100x25)
#define WS_HM     11776   // 1600 (B*V t-means)
#define WS_Z2     13440   // 480000 (b,t,v)
#define WS_XS     493440  // 480000 (b,v,t)
#define WS_CM     973440  // 4,000,000 (b,c,i,j)
#define WS_P      4973440 // bf16 p buffer starts here

__device__ __forceinline__ float waveRed(float v) {
    #pragma unroll
    for (int off = 32; off > 0; off >>= 1) v += __shfl_down(v, off);
    return v;
}

// ---------------- Pass A: x channel stats ----------------
__global__ void k_xstats(const float* __restrict__ x, float* __restrict__ ws) {
    int tid = blockIdx.x * blockDim.x + threadIdx.x;
    int nth = gridDim.x * blockDim.x;
    float a0=0,a1=0,a2=0,m00=0,m01=0,m02=0,m11=0,m12=0,m22=0;
    for (int p = tid; p < N_POS; p += nth) {
        int b = p / 7500; int rem = p - b * 7500;
        const float* xb = x + b * 22500 + rem;
        float x0 = xb[0], x1 = xb[7500], x2 = xb[15000];
        a0+=x0; a1+=x1; a2+=x2;
        m00+=x0*x0; m01+=x0*x1; m02+=x0*x2; m11+=x1*x1; m12+=x1*x2; m22+=x2*x2;
    }
    a0=waveRed(a0); a1=waveRed(a1); a2=waveRed(a2);
    m00=waveRed(m00); m01=waveRed(m01); m02=waveRed(m02);
    m11=waveRed(m11); m12=waveRed(m12); m22=waveRed(m22);
    if ((threadIdx.x & 63) == 0) {
        atomicAdd(&ws[WS_XSUM+0],a0); atomicAdd(&ws[WS_XSUM+1],a1); atomicAdd(&ws[WS_XSUM+2],a2);
        atomicAdd(&ws[WS_XSS+0],m00); atomicAdd(&ws[WS_XSS+1],m01); atomicAdd(&ws[WS_XSS+2],m02);
        atomicAdd(&ws[WS_XSS+3],m11); atomicAdd(&ws[WS_XSS+4],m12); atomicAdd(&ws[WS_XSS+5],m22);
    }
}

// ---------------- sw[c,m] = sum_l weight^2 ----------------
__global__ void k_prepw(const float* __restrict__ weight, float* __restrict__ ws) {
    int idx = blockIdx.x * blockDim.x + threadIdx.x;
    if (idx < 2500) {
        float s = 0;
        #pragma unroll
        for (int l = 0; l < NTL; l++) { float w = weight[idx*NTL + l]; s += w*w; }
        ws[WS_SW + idx] = s;
    }
}

// ---------------- W1 transpose: W1T[c][o] = w1[o][c] ----------------
__global__ void k_prepw1t(const float* __restrict__ w1g, float* __restrict__ ws) {
    int idx = blockIdx.x * 256 + threadIdx.x;
    if (idx < 8192) {
        int c = idx >> 7, o = idx & 127;
        ws[WS_W1T + idx] = w1g[o*64 + c];
    }
}

// ---------------- BN0 folded affine from x moments (exact linearity) ----------------
// h0[ch] = relu(wa0*x0 + wa1*x1 + wa2*x2 + ba), packed float4 per ch.
__global__ void k_prep0(const float* __restrict__ w, const float* __restrict__ bb,
                        const float* __restrict__ g, const float* __restrict__ bt,
                        float* __restrict__ ws) {
    int o = threadIdx.x; // 64
    float inv = 1.0f / (float)N_POS;
    float mx0 = ws[WS_XSUM+0]*inv, mx1 = ws[WS_XSUM+1]*inv, mx2 = ws[WS_XSUM+2]*inv;
    float C00 = ws[WS_XSS+0]*inv - mx0*mx0;
    float C01 = ws[WS_XSS+1]*inv - mx0*mx1;
    float C02 = ws[WS_XSS+2]*inv - mx0*mx2;
    float C11 = ws[WS_XSS+3]*inv - mx1*mx1;
    float C12 = ws[WS_XSS+4]*inv - mx1*mx2;
    float C22 = ws[WS_XSS+5]*inv - mx2*mx2;
    float w0 = w[o*3], w1 = w[o*3+1], w2 = w[o*3+2];
    float mu  = w0*mx0 + w1*mx1 + w2*mx2 + bb[o];
    float var = w0*w0*C00 + w1*w1*C11 + w2*w2*C22
              + 2.f*(w0*w1*C01 + w0*w2*C02 + w1*w2*C12);
    float sc = g[o] / sqrtf(var + 1e-5f);
    float sh = bt[o] - sc*mu;
    ws[WS_WA + o*4 + 0] = sc*w0;
    ws[WS_WA + o*4 + 1] = sc*w1;
    ws[WS_WA + o*4 + 2] = sc*w2;
    ws[WS_WA + o*4 + 3] = sc*bb[o] + sh;
}

// ---------------- z1 GEMM pass (LDS-tiled, 4pos x 8out register tiles) ----
// MODE 0: accumulate z1 sum / sumsq per output into ws (for BN1 stats).
// MODE 1: apply bn1+relu, dot with w2 -> z2 per position; write z2 + stats.
#define ZP_BLOCKS 500
#define ZP_CHUNKS 15
template<int MODE>
__global__ __launch_bounds__(256) void k_zpass(
        const float* __restrict__ x,
        const float* __restrict__ b1g,
        const float* __restrict__ w2g,
        const float* __restrict__ b2g,
        float* __restrict__ ws) {
    __shared__ float smem[12544];         // 50176 B
    float* s_h0  = smem;                  // [64 ch][68 pos-pad]
    float* s_w1t = smem + 4352;           // [64 c][128 o]
    int tid = threadIdx.x;

    for (int i = tid; i < 8192; i += 256) s_w1t[i] = ws[WS_W1T + i];

    int pos = tid & 63, cset = tid >> 6;  // staging mapping
    int pg  = tid >> 4, og  = tid & 15;   // GEMM mapping

    float b1r[8];
    #pragma unroll
    for (int o = 0; o < 8; o++) b1r[o] = b1g[og*8 + o];
    float sc1r[8], sh1r[8], w2r[8], b2v = 0.f;
    if constexpr (MODE == 1) {
        #pragma unroll
        for (int o = 0; o < 8; o++) {
            sc1r[o] = ws[WS_SC1 + og*8 + o];
            sh1r[o] = ws[WS_SH1 + og*8 + o];
            w2r[o]  = w2g[og*8 + o];
        }
        b2v = b2g[0];
    }
    float zs[8], zq[8];
    #pragma unroll
    for (int o = 0; o < 8; o++) { zs[o] = 0.f; zq[o] = 0.f; }
    float z2s = 0.f, z2q = 0.f;

    __syncthreads();

    for (int ci = 0; ci < ZP_CHUNKS; ci++) {
        int chunk = blockIdx.x * ZP_CHUNKS + ci;
        int P = chunk*64 + pos;
        int b = P / 7500, rem = P - b*7500;
        const float* xb = x + b*22500 + rem;
        float x0 = xb[0], x1 = xb[7500], x2 = xb[15000];
        #pragma unroll
        for (int k = 0; k < 16; k++) {
            int ch = cset*16 + k;
            const float4 wa = *(const float4*)&ws[WS_WA + ch*4];
            s_h0[ch*68 + pos] = fmaxf(wa.x*x0 + wa.y*x1 + wa.z*x2 + wa.w, 0.f);
        }
        __syncthreads();

        float acc[4][8];
        #pragma unroll
        for (int p = 0; p < 4; p++)
            #pragma unroll
            for (int o = 0; o < 8; o++) acc[p][o] = 0.f;

        #pragma unroll 4
        for (int c = 0; c < 64; c++) {
            float4 ha = *(const float4*)&s_h0[c*68 + 4*pg];
            float4 wl = *(const float4*)&s_w1t[c*128 + 8*og];
            float4 wh = *(const float4*)&s_w1t[c*128 + 8*og + 4];
            #pragma unroll
            for (int p = 0; p < 4; p++) {
                float hv = ((const float*)&ha)[p];
                #pragma unroll
                for (int o = 0; o < 4; o++) {
                    acc[p][o]   = fmaf(hv, ((const float*)&wl)[o], acc[p][o]);
                    acc[p][o+4] = fmaf(hv, ((const float*)&wh)[o], acc[p][o+4]);
                }
            }
        }

        if constexpr (MODE == 0) {
            #pragma unroll
            for (int o = 0; o < 8; o++) {
                #pragma unroll
                for (int p = 0; p < 4; p++) {
                    float z = acc[p][o] + b1r[o];
                    zs[o] += z; zq[o] += z*z;
                }
            }
            __syncthreads();   // protect s_h0 before next staging
        } else {
            float zp[4];
            #pragma unroll
            for (int p = 0; p < 4; p++) {
                float s = 0.f;
                #pragma unroll
                for (int o = 0; o < 8; o++) {
                    float z = acc[p][o] + b1r[o];
                    s += w2r[o]*fmaxf(sc1r[o]*z + sh1r[o], 0.f);
                }
                zp[p] = s;
            }
            __syncthreads();               // all GEMM reads of s_h0 done
            float* s_z2p = smem;           // [64 pos][17]
            #pragma unroll
            for (int p = 0; p < 4; p++) s_z2p[(4*pg + p)*17 + og] = zp[p];
            __syncthreads();
            if (tid < 64) {
                float z2 = b2v;
                #pragma unroll
                for (int j = 0; j < 16; j++) z2 += s_z2p[tid*17 + j];
                ws[WS_Z2 + chunk*64 + tid] = z2;
                z2s += z2; z2q += z2*z2;
            }
            __syncthreads();               // protect overlay before next staging
        }
    }

    if constexpr (MODE == 0) {
        float* s_part = smem;              // [128 o][17]
        #pragma unroll
        for (int o = 0; o < 8; o++) s_part[(og*8 + o)*17 + pg] = zs[o];
        __syncthreads();
        if (tid < 128) {
            float s = 0.f;
            #pragma unroll
            for (int j = 0; j < 16; j++) s += s_part[tid*17 + j];
            atomicAdd(&ws[WS_Z1SUM + tid], s);
        }
        __syncthreads();
        #pragma unroll
        for (int o = 0; o < 8; o++) s_part[(og*8 + o)*17 + pg] = zq[o];
        __syncthreads();
        if (tid < 128) {
            float s = 0.f;
            #pragma unroll
            for (int j = 0; j < 16; j++) s += s_part[tid*17 + j];
            atomicAdd(&ws[WS_Z1SQ + tid], s);
        }
    } else {
        if (tid < 64) {
            z2s = waveRed(z2s);
            z2q = waveRed(z2q);
            if (tid == 0) { atomicAdd(&ws[WS_Z2SUM], z2s); atomicAdd(&ws[WS_Z2SQ], z2q); }
        }
    }
}

__global__ void k_prep1(const float* __restrict__ g, const float* __restrict__ bt,
                        float* __restrict__ ws) {
    int o = threadIdx.x; // 128
    float inv = 1.0f / (float)N_POS;
    float m = ws[WS_Z1SUM+o]*inv;
    float v = ws[WS_Z1SQ+o]*inv - m*m;
    float sc = g[o] / sqrtf(v + 1e-5f);
    ws[WS_SC1+o] = sc;
    ws[WS_SH1+o] = bt[o] - sc*m;
}

__global__ void k_prep2(const float* __restrict__ g, const float* __restrict__ bt,
                        float* __restrict__ ws) {
    float inv = 1.0f / (float)N_POS;
    float m = ws[WS_Z2SUM]*inv;
    float v = ws[WS_Z2SQ]*inv - m*m;
    float sc = g[0] / sqrtf(v + 1e-5f);
    ws[WS_SC2] = sc;
    ws[WS_SH2] = bt[0] - sc*m;
}

// ---------------- x_series (b,v,t) + per-(b,v) t-mean ----------------
__global__ void k_xs(float* __restrict__ ws) {
    __shared__ float red[128];
    int bid = blockIdx.x;       // b*25+v
    int b = bid / 25, v = bid - b*25;
    float sc = ws[WS_SC2], sh = ws[WS_SH2];
    float local = 0.f;
    for (int t = threadIdx.x; t < NT; t += 128) {
        float val = fmaxf(sc * ws[WS_Z2 + b*7500 + t*25 + v] + sh, 0.f);
        ws[WS_XS + (size_t)bid*NT + t] = val;
        local += val;
    }
    red[threadIdx.x] = local;
    __syncthreads();
    for (int s = 64; s > 0; s >>= 1) {
        if (threadIdx.x < s) red[threadIdx.x] += red[threadIdx.x + s];
        __syncthreads();
    }
    if (threadIdx.x == 0) ws[WS_HM + bid] = red[0] * (1.f/300.f);
}

// ---------------- cm[b,c,i,j] = tanh(x1[b,c,i]-x2[b,c,j]) ----------------
__global__ void k_cm(const float* __restrict__ c1w, const float* __restrict__ c1b,
                     const float* __restrict__ c2w, const float* __restrict__ c2b,
                     float* __restrict__ ws) {
    __shared__ float s_hm[25];
    int bid = blockIdx.x;       // b*100+c
    int b = bid / 100, c = bid - b*100;
    if (threadIdx.x < 25) s_hm[threadIdx.x] = ws[WS_HM + b*25 + threadIdx.x];
    float a1 = c1w[c], d1 = c1b[c], a2 = c2w[c], d2 = c2b[c];
    __syncthreads();
    for (int idx = threadIdx.x; idx < 625; idx += 256) {
        int i = idx / 25, j = idx - i*25;
        ws[WS_CM + (size_t)bid*625 + idx] = tanhf(a1*s_hm[i] + d1 - a2*s_hm[j] - d2);
    }
}

// ---------------- GCs ----------------
__global__ void k_gcs(const float* __restrict__ ws, float* __restrict__ out) {
    int gid = blockIdx.x * 256 + threadIdx.x;
    if (gid < 40000) {
        int b = gid / 625; int rem = gid - b*625; int m = rem % 25;
        float acc = 0.f;
        for (int c = 0; c < 100; c++) {
            float v = ws[WS_CM + ((size_t)(b*100+c))*625 + rem];
            acc += v*v*ws[WS_SW + c*25 + m];
        }
        out[gid] = sqrtf(acc);
    }
}

// ---------------- panelty ----------------
__global__ void k_pan(float* __restrict__ ws) {
    __shared__ float s_colsq[25];
    __shared__ float s_n1, s_r;
    int tid = threadIdx.x;
    int b = blockIdx.x;
    if (tid < 25) s_colsq[tid] = 0.f;
    if (tid == 0) { s_n1 = 0.f; s_r = 0.f; }
    __syncthreads();
    float ln1 = 0.f;
    for (int idx = tid; idx < 625; idx += 256) {
        int j = idx % 25;
        float sq = 0.f;
        for (int c = 0; c < 100; c++) {
            float v = ws[WS_CM + ((size_t)(b*100+c))*625 + idx];
            sq += v*v;
        }
        ln1 += sqrtf(sq);
        atomicAdd(&s_colsq[j], sq);
    }
    ln1 = waveRed(ln1);
    if ((tid & 63) == 0) atomicAdd(&s_n1, ln1);
    __syncthreads();
    if (tid < 25) atomicAdd(&s_r, sqrtf(s_colsq[tid]));
    __syncthreads();
    if (tid == 0) atomicAdd(&ws[WS_PAN], s_n1 + s_r);
}

// ---------------- regularize ----------------
__global__ void k_reg(const float* __restrict__ f0w, const float* __restrict__ f1w,
                      const float* __restrict__ f2w, float* __restrict__ ws) {
    int tid = blockIdx.x * blockDim.x + threadIdx.x;
    int nth = gridDim.x * blockDim.x;
    float a = 0.f;
    for (int i = tid; i < 275250; i += nth) {
        float w;
        if (i < 250000) w = f0w[i];
        else if (i < 275000) w = f1w[i - 250000];
        else w = f2w[i - 275000];
        a += w*w;
    }
    a = waveRed(a);
    if ((threadIdx.x & 63) == 0) atomicAdd(&ws[WS_REG], a);
}

// ---------------- Fc + p per (b,c), fused in LDS ----------------
__global__ __launch_bounds__(256) void k_fcp(
        const float* __restrict__ weight, const float* __restrict__ wnorm,
        __hip_bfloat16* __restrict__ pbuf, const float* __restrict__ ws, int b_base) {
    __shared__ float s_xs[7500];
    __shared__ float s_fc[25*NL];   // 7300
    __shared__ float s_wn[225];
    __shared__ float s_cm[625];
    int tid = threadIdx.x;
    int bid = blockIdx.x;
    int bl = bid / 100, c = bid - bl*100;
    int b = b_base + bl;
    for (int i = tid; i < 225; i += 256) s_wn[i] = weight[c*225 + i] / wnorm[i];
    for (int i = tid; i < 7500; i += 256) s_xs[i] = ws[WS_XS + (size_t)b*7500 + i];
    for (int i = tid; i < 625; i += 256) s_cm[i] = ws[WS_CM + ((size_t)(b*100+c))*625 + i];
    __syncthreads();
    for (int i = tid; i < 25*NL; i += 256) {
        int v = i / NL, t = i - v*NL;
        float f = 0.f;
        #pragma unroll
        for (int l = 0; l < NTL; l++) f += s_xs[v*NT + t + l] * s_wn[v*NTL + l];
        s_fc[i] = f;
    }
    __syncthreads();
    for (int i = tid; i < 25*NL; i += 256) {
        int ii = i / NL, t = i - ii*NL;
        float a = 0.f;
        #pragma unroll
        for (int v = 0; v < 25; v++) a += s_cm[v*25 + ii] * s_fc[v*NL + t];
        pbuf[((size_t)((bl*25 + ii)*100 + c))*NL + t] = __float2bfloat16(a);
    }
}

// ---------------- group MLP f0/f1/f2 + loss ----------------
__global__ __launch_bounds__(256) void k_mlp(
        const __hip_bfloat16* __restrict__ pbuf,
        const float* __restrict__ f0w, const float* __restrict__ f0b,
        const float* __restrict__ f1w, const float* __restrict__ f1b,
        const float* __restrict__ f2w, const float* __restrict__ f2b,
        float* __restrict__ ws, int b_base) {
    __shared__ float s_w1t[1000];   // [o][o2]
    __shared__ float s_loss;
    int tid = threadIdx.x;
    int bid = blockIdx.x;
    int bl = bid / 25, g = bid - bl*25;
    int b = b_base + bl;
    for (int i = tid; i < 1000; i += 256) {
        int o = i / 10, o2 = i - o*10;
        s_w1t[i] = f1w[g*1000 + o2*100 + o];
    }
    if (tid == 0) s_loss = 0.f;
    __syncthreads();
    const __hip_bfloat16* pg = pbuf + ((size_t)(bl*25 + g))*100*NL;
    const float* w0 = f0w + g*10000;
    const float* b0 = f0b + g*100;
    const float* b1 = f1b + g*10;
    const float* w2 = f2w + g*10;
    float b2 = f2b[g];
    float local = 0.f;
    for (int t = tid; t < NL; t += 256) {
        float pr[100];
        #pragma unroll
        for (int cc = 0; cc < 100; cc++) pr[cc] = __bfloat162float(pg[(size_t)cc*NL + t]);
        float acc2[10];
        #pragma unroll
        for (int o2 = 0; o2 < 10; o2++) acc2[o2] = b1[o2];
        for (int o = 0; o < 100; o++) {
            float a = b0[o];
            const float* wr = w0 + o*100;
            #pragma unroll
            for (int cc = 0; cc < 100; cc++) a += wr[cc]*pr[cc];
            a = fmaxf(a, 0.f);
            #pragma unroll
            for (int o2 = 0; o2 < 10; o2++) acc2[o2] += s_w1t[o*10 + o2]*a;
        }
        float z3 = b2;
        #pragma unroll
        for (int o2 = 0; o2 < 10; o2++) z3 += w2[o2]*fmaxf(acc2[o2], 0.f);
        z3 = fmaxf(z3, 0.f);
        if (t < NL-1) {
            float d = ws[WS_XS + ((size_t)(b*25 + g))*NT + t + NTL] - z3;
            local += d*d;
        }
    }
    local = waveRed(local);
    if ((tid & 63) == 0) atomicAdd(&s_loss, local);
    __syncthreads();
    if (tid == 0) atomicAdd(&ws[WS_LOSS], s_loss);
}

// ---------------- final scalars ----------------
__global__ void k_final(float* __restrict__ out, const float* __restrict__ ws) {
    out[40000] = ws[WS_LOSS] * (1.f / 465600.f);
    out[40001] = 1e-4f * ws[WS_PAN];
    out[40002] = 1e-4f * ws[WS_REG];
}

extern "C" void kernel_launch(void* const* d_in, const int* in_sizes, int n_in,
                              void* d_out, int out_size, void* d_ws, size_t ws_size,
                              hipStream_t stream) {
    const float* x      = (const float*)d_in[0];
    const float* weight = (const float*)d_in[1];
    const float* wnorm  = (const float*)d_in[2];
    const float* fb0_w  = (const float*)d_in[3];
    const float* fb0_b  = (const float*)d_in[4];
    const float* bn0_g  = (const float*)d_in[5];
    const float* bn0_b  = (const float*)d_in[6];
    const float* fb1_w  = (const float*)d_in[7];
    const float* fb1_b  = (const float*)d_in[8];
    const float* bn1_g  = (const float*)d_in[9];
    const float* bn1_b  = (const float*)d_in[10];
    const float* fb2_w  = (const float*)d_in[11];
    const float* fb2_b  = (const float*)d_in[12];
    const float* bn2_g  = (const float*)d_in[13];
    const float* bn2_b  = (const float*)d_in[14];
    const float* c1_w   = (const float*)d_in[15];
    const float* c1_b   = (const float*)d_in[16];
    const float* c2_w   = (const float*)d_in[17];
    const float* c2_b   = (const float*)d_in[18];
    const float* f0_w   = (const float*)d_in[19];
    const float* f0_b   = (const float*)d_in[20];
    const float* f1_w   = (const float*)d_in[21];
    const float* f1_b   = (const float*)d_in[22];
    const float* f2_w   = (const float*)d_in[23];
    const float* f2_b   = (const float*)d_in[24];

    float* ws  = (float*)d_ws;
    float* out = (float*)d_out;
    __hip_bfloat16* pbuf = (__hip_bfloat16*)(ws + WS_P);

    // zero accumulators (floats 0..659)
    hipMemsetAsync(d_ws, 0, 2640, stream);

    k_xstats<<<512, 256, 0, stream>>>(x, ws);
    k_prepw<<<10, 256, 0, stream>>>(weight, ws);
    k_prepw1t<<<32, 256, 0, stream>>>(fb1_w, ws);
    k_prep0<<<1, 64, 0, stream>>>(fb0_w, fb0_b, bn0_g, bn0_b, ws);
    k_zpass<0><<<ZP_BLOCKS, 256, 0, stream>>>(x, fb1_b, fb2_w, fb2_b, ws);
    k_prep1<<<1, 128, 0, stream>>>(bn1_g, bn1_b, ws);
    k_zpass<1><<<ZP_BLOCKS, 256, 0, stream>>>(x, fb1_b, fb2_w, fb2_b, ws);
    k_prep2<<<1, 1, 0, stream>>>(bn2_g, bn2_b, ws);
    k_xs<<<1600, 128, 0, stream>>>(ws);
    k_cm<<<6400, 256, 0, stream>>>(c1_w, c1_b, c2_w, c2_b, ws);
    k_gcs<<<157, 256, 0, stream>>>(ws, out);
    k_pan<<<64, 256, 0, stream>>>(ws);
    k_reg<<<256, 256, 0, stream>>>(f0_w, f1_w, f2_w, ws);

    // Adaptive b-chunking for the bf16 p buffer (deterministic in ws_size ->
    // identical work every call; graph-capture safe).
    const size_t p_bytes_per_b = (size_t)25*100*NL*sizeof(__hip_bfloat16); // 1.46 MB
    size_t fixed_bytes = (size_t)WS_P * sizeof(float);
    size_t avail = ws_size > fixed_bytes ? ws_size - fixed_bytes : 0;
    int bs = (int)(avail / p_bytes_per_b);
    if (bs > 64) bs = 64;
    if (bs < 1)  bs = 1;
    for (int b0 = 0; b0 < 64; b0 += bs) {
        int nb = (64 - b0) < bs ? (64 - b0) : bs;
        k_fcp<<<nb*100, 256, 0, stream>>>(weight, wnorm, pbuf, ws, b0);
        k_mlp<<<nb*25, 256, 0, stream>>>(pbuf, f0_w, f0_b, f1_w, f1_b, f2_w, f2_b, ws, b0);
    }
    k_final<<<1, 1, 0, stream>>>(out, ws);
}

// Round 6
// 1041.947 us; speedup vs baseline: 1.3084x; 1.0811x over previous
//
#include <hip/hip_runtime.h>
#include <hip/hip_bf16.h>
#include <string.h>

// Problem constants
#define N_POS 480000      // B*T*V = 64*300*25
#define NB    64
#define NT    300
#define NV    25
#define NCC   100
#define NTL   9
#define NL    292         // T - TL + 1

// Workspace float offsets
#define WS_XSUM   0       // 3
#define WS_XSS    3       // 6 (m00,m01,m02,m11,m12,m22)
#define WS_Z1SUM  140     // 128 (atomic acc)
#define WS_Z1SQ   268     // 128 (atomic acc)
#define WS_SC1    396     // 128
#define WS_SH1    524     // 128
#define WS_Z2SUM  652
#define WS_Z2SQ   653
#define WS_SC2    654
#define WS_SH2    655
#define WS_LOSS   656
#define WS_PAN    657
#define WS_REG    658
#define WS_WA     768     // 256: packed (sc*w0, sc*w1, sc*w2, ba) per ch
#define WS_W1T    1024    // 8192: W1 transposed [c][o]
#define WS_SW     9216    // 2500 = sum_l weight^2 (100x25)
#define WS_HM     11776   // 1600 (B*V t-means)
#define WS_Z2     13440   // 480000 (b,t,v)
#define WS_XS     493440  // 480000 (b,v,t)
#define WS_CM     973440  // 4,000,000 (b,c,i,j)
#define WS_P      4973440 // bf16 p buffer starts here

__device__ __forceinline__ float waveRed(float v) {
    #pragma unroll
    for (int off = 32; off > 0; off >>= 1) v += __shfl_down(v, off);
    return v;
}

__device__ __forceinline__ unsigned pack2bf(float a, float b) {
    __hip_bfloat16 ha = __float2bfloat16(a), hb = __float2bfloat16(b);
    unsigned short ua, ub;
    memcpy(&ua, &ha, 2); memcpy(&ub, &hb, 2);
    return (unsigned)ua | ((unsigned)ub << 16);
}

// ---------------- Pass A: x channel stats ----------------
__global__ void k_xstats(const float* __restrict__ x, float* __restrict__ ws) {
    int tid = blockIdx.x * blockDim.x + threadIdx.x;
    int nth = gridDim.x * blockDim.x;
    float a0=0,a1=0,a2=0,m00=0,m01=0,m02=0,m11=0,m12=0,m22=0;
    for (int p = tid; p < N_POS; p += nth) {
        int b = p / 7500; int rem = p - b * 7500;
        const float* xb = x + b * 22500 + rem;
        float x0 = xb[0], x1 = xb[7500], x2 = xb[15000];
        a0+=x0; a1+=x1; a2+=x2;
        m00+=x0*x0; m01+=x0*x1; m02+=x0*x2; m11+=x1*x1; m12+=x1*x2; m22+=x2*x2;
    }
    a0=waveRed(a0); a1=waveRed(a1); a2=waveRed(a2);
    m00=waveRed(m00); m01=waveRed(m01); m02=waveRed(m02);
    m11=waveRed(m11); m12=waveRed(m12); m22=waveRed(m22);
    if ((threadIdx.x & 63) == 0) {
        atomicAdd(&ws[WS_XSUM+0],a0); atomicAdd(&ws[WS_XSUM+1],a1); atomicAdd(&ws[WS_XSUM+2],a2);
        atomicAdd(&ws[WS_XSS+0],m00); atomicAdd(&ws[WS_XSS+1],m01); atomicAdd(&ws[WS_XSS+2],m02);
        atomicAdd(&ws[WS_XSS+3],m11); atomicAdd(&ws[WS_XSS+4],m12); atomicAdd(&ws[WS_XSS+5],m22);
    }
}

// ---------------- sw[c,m] = sum_l weight^2 ----------------
__global__ void k_prepw(const float* __restrict__ weight, float* __restrict__ ws) {
    int idx = blockIdx.x * blockDim.x + threadIdx.x;
    if (idx < 2500) {
        float s = 0;
        #pragma unroll
        for (int l = 0; l < NTL; l++) { float w = weight[idx*NTL + l]; s += w*w; }
        ws[WS_SW + idx] = s;
    }
}

// ---------------- W1 transpose: W1T[c][o] = w1[o][c] ----------------
__global__ void k_prepw1t(const float* __restrict__ w1g, float* __restrict__ ws) {
    int idx = blockIdx.x * 256 + threadIdx.x;
    if (idx < 8192) {
        int c = idx >> 7, o = idx & 127;
        ws[WS_W1T + idx] = w1g[o*64 + c];
    }
}

// ---------------- BN0 folded affine from x moments (exact linearity) ----------------
__global__ void k_prep0(const float* __restrict__ w, const float* __restrict__ bb,
                        const float* __restrict__ g, const float* __restrict__ bt,
                        float* __restrict__ ws) {
    int o = threadIdx.x; // 64
    float inv = 1.0f / (float)N_POS;
    float mx0 = ws[WS_XSUM+0]*inv, mx1 = ws[WS_XSUM+1]*inv, mx2 = ws[WS_XSUM+2]*inv;
    float C00 = ws[WS_XSS+0]*inv - mx0*mx0;
    float C01 = ws[WS_XSS+1]*inv - mx0*mx1;
    float C02 = ws[WS_XSS+2]*inv - mx0*mx2;
    float C11 = ws[WS_XSS+3]*inv - mx1*mx1;
    float C12 = ws[WS_XSS+4]*inv - mx1*mx2;
    float C22 = ws[WS_XSS+5]*inv - mx2*mx2;
    float w0 = w[o*3], w1 = w[o*3+1], w2 = w[o*3+2];
    float mu  = w0*mx0 + w1*mx1 + w2*mx2 + bb[o];
    float var = w0*w0*C00 + w1*w1*C11 + w2*w2*C22
              + 2.f*(w0*w1*C01 + w0*w2*C02 + w1*w2*C12);
    float sc = g[o] / sqrtf(var + 1e-5f);
    float sh = bt[o] - sc*mu;
    ws[WS_WA + o*4 + 0] = sc*w0;
    ws[WS_WA + o*4 + 1] = sc*w1;
    ws[WS_WA + o*4 + 2] = sc*w2;
    ws[WS_WA + o*4 + 3] = sc*bb[o] + sh;
}

// ---------------- z1 GEMM pass (LDS-tiled, 4pos x 8out register tiles) ----
#define ZP_BLOCKS 500
#define ZP_CHUNKS 15
template<int MODE>
__global__ __launch_bounds__(256) void k_zpass(
        const float* __restrict__ x,
        const float* __restrict__ b1g,
        const float* __restrict__ w2g,
        const float* __restrict__ b2g,
        float* __restrict__ ws) {
    __shared__ float smem[12544];         // 50176 B
    float* s_h0  = smem;                  // [64 ch][68 pos-pad]
    float* s_w1t = smem + 4352;           // [64 c][128 o]
    int tid = threadIdx.x;

    for (int i = tid; i < 8192; i += 256) s_w1t[i] = ws[WS_W1T + i];

    int pos = tid & 63, cset = tid >> 6;  // staging mapping
    int pg  = tid >> 4, og  = tid & 15;   // GEMM mapping

    float b1r[8];
    #pragma unroll
    for (int o = 0; o < 8; o++) b1r[o] = b1g[og*8 + o];
    float sc1r[8], sh1r[8], w2r[8], b2v = 0.f;
    if constexpr (MODE == 1) {
        #pragma unroll
        for (int o = 0; o < 8; o++) {
            sc1r[o] = ws[WS_SC1 + og*8 + o];
            sh1r[o] = ws[WS_SH1 + og*8 + o];
            w2r[o]  = w2g[og*8 + o];
        }
        b2v = b2g[0];
    }
    float zs[8], zq[8];
    #pragma unroll
    for (int o = 0; o < 8; o++) { zs[o] = 0.f; zq[o] = 0.f; }
    float z2s = 0.f, z2q = 0.f;

    __syncthreads();

    for (int ci = 0; ci < ZP_CHUNKS; ci++) {
        int chunk = blockIdx.x * ZP_CHUNKS + ci;
        int P = chunk*64 + pos;
        int b = P / 7500, rem = P - b*7500;
        const float* xb = x + b*22500 + rem;
        float x0 = xb[0], x1 = xb[7500], x2 = xb[15000];
        #pragma unroll
        for (int k = 0; k < 16; k++) {
            int ch = cset*16 + k;
            const float4 wa = *(const float4*)&ws[WS_WA + ch*4];
            s_h0[ch*68 + pos] = fmaxf(wa.x*x0 + wa.y*x1 + wa.z*x2 + wa.w, 0.f);
        }
        __syncthreads();

        float acc[4][8];
        #pragma unroll
        for (int p = 0; p < 4; p++)
            #pragma unroll
            for (int o = 0; o < 8; o++) acc[p][o] = 0.f;

        #pragma unroll 4
        for (int c = 0; c < 64; c++) {
            float4 ha = *(const float4*)&s_h0[c*68 + 4*pg];
            float4 wl = *(const float4*)&s_w1t[c*128 + 8*og];
            float4 wh = *(const float4*)&s_w1t[c*128 + 8*og + 4];
            #pragma unroll
            for (int p = 0; p < 4; p++) {
                float hv = ((const float*)&ha)[p];
                #pragma unroll
                for (int o = 0; o < 4; o++) {
                    acc[p][o]   = fmaf(hv, ((const float*)&wl)[o], acc[p][o]);
                    acc[p][o+4] = fmaf(hv, ((const float*)&wh)[o], acc[p][o+4]);
                }
            }
        }

        if constexpr (MODE == 0) {
            #pragma unroll
            for (int o = 0; o < 8; o++) {
                #pragma unroll
                for (int p = 0; p < 4; p++) {
                    float z = acc[p][o] + b1r[o];
                    zs[o] += z; zq[o] += z*z;
                }
            }
            __syncthreads();   // protect s_h0 before next staging
        } else {
            float zp[4];
            #pragma unroll
            for (int p = 0; p < 4; p++) {
                float s = 0.f;
                #pragma unroll
                for (int o = 0; o < 8; o++) {
                    float z = acc[p][o] + b1r[o];
                    s += w2r[o]*fmaxf(sc1r[o]*z + sh1r[o], 0.f);
                }
                zp[p] = s;
            }
            __syncthreads();               // all GEMM reads of s_h0 done
            float* s_z2p = smem;           // [64 pos][17]
            #pragma unroll
            for (int p = 0; p < 4; p++) s_z2p[(4*pg + p)*17 + og] = zp[p];
            __syncthreads();
            if (tid < 64) {
                float z2 = b2v;
                #pragma unroll
                for (int j = 0; j < 16; j++) z2 += s_z2p[tid*17 + j];
                ws[WS_Z2 + chunk*64 + tid] = z2;
                z2s += z2; z2q += z2*z2;
            }
            __syncthreads();               // protect overlay before next staging
        }
    }

    if constexpr (MODE == 0) {
        float* s_part = smem;              // [128 o][17]
        #pragma unroll
        for (int o = 0; o < 8; o++) s_part[(og*8 + o)*17 + pg] = zs[o];
        __syncthreads();
        if (tid < 128) {
            float s = 0.f;
            #pragma unroll
            for (int j = 0; j < 16; j++) s += s_part[tid*17 + j];
            atomicAdd(&ws[WS_Z1SUM + tid], s);
        }
        __syncthreads();
        #pragma unroll
        for (int o = 0; o < 8; o++) s_part[(og*8 + o)*17 + pg] = zq[o];
        __syncthreads();
        if (tid < 128) {
            float s = 0.f;
            #pragma unroll
            for (int j = 0; j < 16; j++) s += s_part[tid*17 + j];
            atomicAdd(&ws[WS_Z1SQ + tid], s);
        }
    } else {
        if (tid < 64) {
            z2s = waveRed(z2s);
            z2q = waveRed(z2q);
            if (tid == 0) { atomicAdd(&ws[WS_Z2SUM], z2s); atomicAdd(&ws[WS_Z2SQ], z2q); }
        }
    }
}

__global__ void k_prep1(const float* __restrict__ g, const float* __restrict__ bt,
                        float* __restrict__ ws) {
    int o = threadIdx.x; // 128
    float inv = 1.0f / (float)N_POS;
    float m = ws[WS_Z1SUM+o]*inv;
    float v = ws[WS_Z1SQ+o]*inv - m*m;
    float sc = g[o] / sqrtf(v + 1e-5f);
    ws[WS_SC1+o] = sc;
    ws[WS_SH1+o] = bt[o] - sc*m;
}

__global__ void k_prep2(const float* __restrict__ g, const float* __restrict__ bt,
                        float* __restrict__ ws) {
    float inv = 1.0f / (float)N_POS;
    float m = ws[WS_Z2SUM]*inv;
    float v = ws[WS_Z2SQ]*inv - m*m;
    float sc = g[0] / sqrtf(v + 1e-5f);
    ws[WS_SC2] = sc;
    ws[WS_SH2] = bt[0] - sc*m;
}

// ---------------- x_series (b,v,t) + per-(b,v) t-mean ----------------
__global__ void k_xs(float* __restrict__ ws) {
    __shared__ float red[128];
    int bid = blockIdx.x;       // b*25+v
    int b = bid / 25, v = bid - b*25;
    float sc = ws[WS_SC2], sh = ws[WS_SH2];
    float local = 0.f;
    for (int t = threadIdx.x; t < NT; t += 128) {
        float val = fmaxf(sc * ws[WS_Z2 + b*7500 + t*25 + v] + sh, 0.f);
        ws[WS_XS + (size_t)bid*NT + t] = val;
        local += val;
    }
    red[threadIdx.x] = local;
    __syncthreads();
    for (int s = 64; s > 0; s >>= 1) {
        if (threadIdx.x < s) red[threadIdx.x] += red[threadIdx.x + s];
        __syncthreads();
    }
    if (threadIdx.x == 0) ws[WS_HM + bid] = red[0] * (1.f/300.f);
}

// ---------------- cm[b,c,i,j] = tanh(x1[b,c,i]-x2[b,c,j]) ----------------
__global__ void k_cm(const float* __restrict__ c1w, const float* __restrict__ c1b,
                     const float* __restrict__ c2w, const float* __restrict__ c2b,
                     float* __restrict__ ws) {
    __shared__ float s_hm[25];
    int bid = blockIdx.x;       // b*100+c
    int b = bid / 100, c = bid - b*100;
    if (threadIdx.x < 25) s_hm[threadIdx.x] = ws[WS_HM + b*25 + threadIdx.x];
    float a1 = c1w[c], d1 = c1b[c], a2 = c2w[c], d2 = c2b[c];
    __syncthreads();
    for (int idx = threadIdx.x; idx < 625; idx += 256) {
        int i = idx / 25, j = idx - i*25;
        ws[WS_CM + (size_t)bid*625 + idx] = tanhf(a1*s_hm[i] + d1 - a2*s_hm[j] - d2);
    }
}

// ---------------- GCs ----------------
__global__ void k_gcs(const float* __restrict__ ws, float* __restrict__ out) {
    int gid = blockIdx.x * 256 + threadIdx.x;
    if (gid < 40000) {
        int b = gid / 625; int rem = gid - b*625; int m = rem % 25;
        float acc = 0.f;
        for (int c = 0; c < 100; c++) {
            float v = ws[WS_CM + ((size_t)(b*100+c))*625 + rem];
            acc += v*v*ws[WS_SW + c*25 + m];
        }
        out[gid] = sqrtf(acc);
    }
}

// ---------------- panelty ----------------
__global__ void k_pan(float* __restrict__ ws) {
    __shared__ float s_colsq[25];
    __shared__ float s_n1, s_r;
    int tid = threadIdx.x;
    int b = blockIdx.x;
    if (tid < 25) s_colsq[tid] = 0.f;
    if (tid == 0) { s_n1 = 0.f; s_r = 0.f; }
    __syncthreads();
    float ln1 = 0.f;
    for (int idx = tid; idx < 625; idx += 256) {
        int j = idx % 25;
        float sq = 0.f;
        for (int c = 0; c < 100; c++) {
            float v = ws[WS_CM + ((size_t)(b*100+c))*625 + idx];
            sq += v*v;
        }
        ln1 += sqrtf(sq);
        atomicAdd(&s_colsq[j], sq);
    }
    ln1 = waveRed(ln1);
    if ((tid & 63) == 0) atomicAdd(&s_n1, ln1);
    __syncthreads();
    if (tid < 25) atomicAdd(&s_r, sqrtf(s_colsq[tid]));
    __syncthreads();
    if (tid == 0) atomicAdd(&ws[WS_PAN], s_n1 + s_r);
}

// ---------------- regularize ----------------
__global__ void k_reg(const float* __restrict__ f0w, const float* __restrict__ f1w,
                      const float* __restrict__ f2w, float* __restrict__ ws) {
    int tid = blockIdx.x * blockDim.x + threadIdx.x;
    int nth = gridDim.x * blockDim.x;
    float a = 0.f;
    for (int i = tid; i < 275250; i += nth) {
        float w;
        if (i < 250000) w = f0w[i];
        else if (i < 275000) w = f1w[i - 250000];
        else w = f2w[i - 275000];
        a += w*w;
    }
    a = waveRed(a);
    if ((threadIdx.x & 63) == 0) atomicAdd(&ws[WS_REG], a);
}

// ---------------- Fc + p per (b,c), register-tiled, t-split halves ----------
// half 0: t in [0,148); half 1: t in [148,292) (len 144)
#define XP 156   // xs row pad (needs up to 156 elems)
#define FP 152   // fc row pad (tail b128 reads up to idx 151)
__global__ __launch_bounds__(256) void k_fcp(
        const float* __restrict__ weight, const float* __restrict__ wnorm,
        __hip_bfloat16* __restrict__ pbuf, const float* __restrict__ ws, int b_base) {
    __shared__ float s_xs[25*XP];   // 3900
    __shared__ float s_fc[25*FP];   // 3800
    __shared__ float s_wn[225];
    __shared__ float s_cm[625];
    int tid = threadIdx.x;
    int bid = blockIdx.x;
    int bl = bid / 100, c = bid - bl*100;
    int b = b_base + bl;

    for (int i = tid; i < 225; i += 256) s_wn[i] = weight[c*225 + i] / wnorm[i];
    for (int i = tid; i < 625; i += 256) s_cm[i] = ws[WS_CM + ((size_t)(b*100+c))*625 + i];

    #pragma unroll
    for (int h = 0; h < 2; h++) {
        const int t_base = h ? 148 : 0;
        const int TH     = h ? 144 : 148;   // half length
        const int NTQ4   = TH / 4;          // fc tiles per row (37 / 36, exact)
        const int NPV    = ((TH + 7) / 8);  // pv t-tiles (19 / 18)

        // stage xs rows [v][0..TH+8)
        for (int i = tid; i < 25*XP; i += 256) {
            int v = i / XP, u = i - v*XP;
            if (u < TH + 8) s_xs[i] = ws[WS_XS + (size_t)(b*25+v)*NT + t_base + u];
        }
        __syncthreads();

        // fc: task = v*NTQ4 + tq, 4 t's per task
        for (int task = tid; task < 25*NTQ4; task += 256) {
            int v = task / NTQ4, tq = task - v*NTQ4;
            int t0 = tq*4;
            float4 xa = *(const float4*)&s_xs[v*XP + t0];
            float4 xb = *(const float4*)&s_xs[v*XP + t0 + 4];
            float4 xc = *(const float4*)&s_xs[v*XP + t0 + 8];
            float xr[12];
            xr[0]=xa.x; xr[1]=xa.y; xr[2]=xa.z; xr[3]=xa.w;
            xr[4]=xb.x; xr[5]=xb.y; xr[6]=xb.z; xr[7]=xb.w;
            xr[8]=xc.x; xr[9]=xc.y; xr[10]=xc.z; xr[11]=xc.w;
            float f[4];
            #pragma unroll
            for (int k = 0; k < 4; k++) f[k] = 0.f;
            #pragma unroll
            for (int l = 0; l < NTL; l++) {
                float w = s_wn[v*NTL + l];
                #pragma unroll
                for (int k = 0; k < 4; k++) f[k] = fmaf(xr[k + l], w, f[k]);
            }
            *(float4*)&s_fc[v*FP + t0] = make_float4(f[0], f[1], f[2], f[3]);
        }
        __syncthreads();

        // PV: task = tq*25 + ii, 8 t's per task
        for (int task = tid; task < NPV*25; task += 256) {
            int tq = task / 25, ii = task - tq*25;
            int t0 = tq*8;
            float cmv[25];
            #pragma unroll
            for (int v = 0; v < 25; v++) cmv[v] = s_cm[v*25 + ii];
            float acc[8];
            #pragma unroll
            for (int k = 0; k < 8; k++) acc[k] = 0.f;
            #pragma unroll
            for (int v = 0; v < 25; v++) {
                float4 f0 = *(const float4*)&s_fc[v*FP + t0];
                float4 f1 = *(const float4*)&s_fc[v*FP + t0 + 4];
                float cv = cmv[v];
                acc[0] = fmaf(cv, f0.x, acc[0]);
                acc[1] = fmaf(cv, f0.y, acc[1]);
                acc[2] = fmaf(cv, f0.z, acc[2]);
                acc[3] = fmaf(cv, f0.w, acc[3]);
                acc[4] = fmaf(cv, f1.x, acc[4]);
                acc[5] = fmaf(cv, f1.y, acc[5]);
                acc[6] = fmaf(cv, f1.z, acc[6]);
                acc[7] = fmaf(cv, f1.w, acc[7]);
            }
            size_t row = (size_t)((bl*25 + ii)*100 + c);
            size_t gbase = row*NL + t_base + t0;
            unsigned p0 = pack2bf(acc[0], acc[1]);
            unsigned p1 = pack2bf(acc[2], acc[3]);
            if (t0 + 8 <= TH) {
                unsigned p2 = pack2bf(acc[4], acc[5]);
                unsigned p3 = pack2bf(acc[6], acc[7]);
                *reinterpret_cast<uint2*>(pbuf + gbase)     = make_uint2(p0, p1);
                *reinterpret_cast<uint2*>(pbuf + gbase + 4) = make_uint2(p2, p3);
            } else {
                // tail (only h=0, tq=18: 4 valid t's)
                *reinterpret_cast<uint2*>(pbuf + gbase) = make_uint2(p0, p1);
            }
        }
        __syncthreads();
    }
}

// ---------------- group MLP f0/f1/f2 + loss ----------------
__global__ __launch_bounds__(256) void k_mlp(
        const __hip_bfloat16* __restrict__ pbuf,
        const float* __restrict__ f0w, const float* __restrict__ f0b,
        const float* __restrict__ f1w, const float* __restrict__ f1b,
        const float* __restrict__ f2w, const float* __restrict__ f2b,
        float* __restrict__ ws, int b_base) {
    __shared__ float s_w1t[1000];   // [o][o2]
    __shared__ float s_loss;
    int tid = threadIdx.x;
    int bid = blockIdx.x;
    int bl = bid / 25, g = bid - bl*25;
    int b = b_base + bl;
    for (int i = tid; i < 1000; i += 256) {
        int o = i / 10, o2 = i - o*10;
        s_w1t[i] = f1w[g*1000 + o2*100 + o];
    }
    if (tid == 0) s_loss = 0.f;
    __syncthreads();
    const __hip_bfloat16* pg = pbuf + ((size_t)(bl*25 + g))*100*NL;
    const float* w0 = f0w + g*10000;
    const float* b0 = f0b + g*100;
    const float* b1 = f1b + g*10;
    const float* w2 = f2w + g*10;
    float b2 = f2b[g];
    float local = 0.f;
    for (int t = tid; t < NL; t += 256) {
        float pr[100];
        #pragma unroll
        for (int cc = 0; cc < 100; cc++) pr[cc] = __bfloat162float(pg[(size_t)cc*NL + t]);
        float acc2[10];
        #pragma unroll
        for (int o2 = 0; o2 < 10; o2++) acc2[o2] = b1[o2];
        for (int o = 0; o < 100; o++) {
            float a = b0[o];
            const float* wr = w0 + o*100;
            #pragma unroll
            for (int cc = 0; cc < 100; cc++) a += wr[cc]*pr[cc];
            a = fmaxf(a, 0.f);
            #pragma unroll
            for (int o2 = 0; o2 < 10; o2++) acc2[o2] += s_w1t[o*10 + o2]*a;
        }
        float z3 = b2;
        #pragma unroll
        for (int o2 = 0; o2 < 10; o2++) z3 += w2[o2]*fmaxf(acc2[o2], 0.f);
        z3 = fmaxf(z3, 0.f);
        if (t < NL-1) {
            float d = ws[WS_XS + ((size_t)(b*25 + g))*NT + t + NTL] - z3;
            local += d*d;
        }
    }
    local = waveRed(local);
    if ((tid & 63) == 0) atomicAdd(&s_loss, local);
    __syncthreads();
    if (tid == 0) atomicAdd(&ws[WS_LOSS], s_loss);
}

// ---------------- final scalars ----------------
__global__ void k_final(float* __restrict__ out, const float* __restrict__ ws) {
    out[40000] = ws[WS_LOSS] * (1.f / 465600.f);
    out[40001] = 1e-4f * ws[WS_PAN];
    out[40002] = 1e-4f * ws[WS_REG];
}

extern "C" void kernel_launch(void* const* d_in, const int* in_sizes, int n_in,
                              void* d_out, int out_size, void* d_ws, size_t ws_size,
                              hipStream_t stream) {
    const float* x      = (const float*)d_in[0];
    const float* weight = (const float*)d_in[1];
    const float* wnorm  = (const float*)d_in[2];
    const float* fb0_w  = (const float*)d_in[3];
    const float* fb0_b  = (const float*)d_in[4];
    const float* bn0_g  = (const float*)d_in[5];
    const float* bn0_b  = (const float*)d_in[6];
    const float* fb1_w  = (const float*)d_in[7];
    const float* fb1_b  = (const float*)d_in[8];
    const float* bn1_g  = (const float*)d_in[9];
    const float* bn1_b  = (const float*)d_in[10];
    const float* fb2_w  = (const float*)d_in[11];
    const float* fb2_b  = (const float*)d_in[12];
    const float* bn2_g  = (const float*)d_in[13];
    const float* bn2_b  = (const float*)d_in[14];
    const float* c1_w   = (const float*)d_in[15];
    const float* c1_b   = (const float*)d_in[16];
    const float* c2_w   = (const float*)d_in[17];
    const float* c2_b   = (const float*)d_in[18];
    const float* f0_w   = (const float*)d_in[19];
    const float* f0_b   = (const float*)d_in[20];
    const float* f1_w   = (const float*)d_in[21];
    const float* f1_b   = (const float*)d_in[22];
    const float* f2_w   = (const float*)d_in[23];
    const float* f2_b   = (const float*)d_in[24];

    float* ws  = (float*)d_ws;
    float* out = (float*)d_out;
    __hip_bfloat16* pbuf = (__hip_bfloat16*)(ws + WS_P);

    // zero accumulators (floats 0..659)
    hipMemsetAsync(d_ws, 0, 2640, stream);

    k_xstats<<<512, 256, 0, stream>>>(x, ws);
    k_prepw<<<10, 256, 0, stream>>>(weight, ws);
    k_prepw1t<<<32, 256, 0, stream>>>(fb1_w, ws);
    k_prep0<<<1, 64, 0, stream>>>(fb0_w, fb0_b, bn0_g, bn0_b, ws);
    k_zpass<0><<<ZP_BLOCKS, 256, 0, stream>>>(x, fb1_b, fb2_w, fb2_b, ws);
    k_prep1<<<1, 128, 0, stream>>>(bn1_g, bn1_b, ws);
    k_zpass<1><<<ZP_BLOCKS, 256, 0, stream>>>(x, fb1_b, fb2_w, fb2_b, ws);
    k_prep2<<<1, 1, 0, stream>>>(bn2_g, bn2_b, ws);
    k_xs<<<1600, 128, 0, stream>>>(ws);
    k_cm<<<6400, 256, 0, stream>>>(c1_w, c1_b, c2_w, c2_b, ws);
    k_gcs<<<157, 256, 0, stream>>>(ws, out);
    k_pan<<<64, 256, 0, stream>>>(ws);
    k_reg<<<256, 256, 0, stream>>>(f0_w, f1_w, f2_w, ws);

    // Adaptive b-chunking for the bf16 p buffer (deterministic in ws_size ->
    // identical work every call; graph-capture safe).
    const size_t p_bytes_per_b = (size_t)25*100*NL*sizeof(__hip_bfloat16); // 1.46 MB
    size_t fixed_bytes = (size_t)WS_P * sizeof(float);
    size_t avail = ws_size > fixed_bytes ? ws_size - fixed_bytes : 0;
    int bs = (int)(avail / p_bytes_per_b);
    if (bs > 64) bs = 64;
    if (bs < 1)  bs = 1;
    for (int b0 = 0; b0 < 64; b0 += bs) {
        int nb = (64 - b0) < bs ? (64 - b0) : bs;
        k_fcp<<<nb*100, 256, 0, stream>>>(weight, wnorm, pbuf, ws, b0);
        k_mlp<<<nb*25, 256, 0, stream>>>(pbuf, f0_w, f0_b, f1_w, f1_b, f2_w, f2_b, ws, b0);
    }
    k_final<<<1, 1, 0, stream>>>(out, ws);
}

// Round 7
// 1026.550 us; speedup vs baseline: 1.3280x; 1.0150x over previous
//
#include <hip/hip_runtime.h>
#include <hip/hip_bf16.h>
#include <string.h>

// Problem constants
#define N_POS 480000      // B*T*V = 64*300*25
#define NB    64
#define NT    300
#define NV    25
#define NCC   100
#define NTL   9
#define NL    292         // T - TL + 1

// Workspace float offsets
#define WS_XSUM   0       // 3
#define WS_XSS    3       // 6 (m00,m01,m02,m11,m12,m22)
#define WS_Z1SUM  140     // 128 (atomic acc)
#define WS_Z1SQ   268     // 128 (atomic acc)
#define WS_SC1    396     // 128
#define WS_SH1    524     // 128
#define WS_Z2SUM  652
#define WS_Z2SQ   653
#define WS_SC2    654
#define WS_SH2    655
#define WS_LOSS   656
#define WS_PAN    657
#define WS_REG    658
#define WS_WA     768     // 256: packed (sc*w0, sc*w1, sc*w2, ba) per ch
#define WS_W1T    1024    // 8192: W1 transposed [c][o]
#define WS_SW     9216    // 2500 = sum_l weight^2 (100x25)
#define WS_HM     11776   // 1600 (B*V t-means)
#define WS_Z2     13440   // 480000 (b,t,v)
#define WS_XS     493440  // 480000 (b,v,t)
#define WS_CM     973440  // 4,000,000 (b,c,i,j)
#define WS_P      4973440 // bf16 p buffer starts here

__device__ __forceinline__ float waveRed(float v) {
    #pragma unroll
    for (int off = 32; off > 0; off >>= 1) v += __shfl_down(v, off);
    return v;
}

__device__ __forceinline__ unsigned pack2bf(float a, float b) {
    __hip_bfloat16 ha = __float2bfloat16(a), hb = __float2bfloat16(b);
    unsigned short ua, ub;
    memcpy(&ua, &ha, 2); memcpy(&ub, &hb, 2);
    return (unsigned)ua | ((unsigned)ub << 16);
}

// ---------------- Pass A: x channel stats ----------------
__global__ void k_xstats(const float* __restrict__ x, float* __restrict__ ws) {
    int tid = blockIdx.x * blockDim.x + threadIdx.x;
    int nth = gridDim.x * blockDim.x;
    float a0=0,a1=0,a2=0,m00=0,m01=0,m02=0,m11=0,m12=0,m22=0;
    for (int p = tid; p < N_POS; p += nth) {
        int b = p / 7500; int rem = p - b * 7500;
        const float* xb = x + b * 22500 + rem;
        float x0 = xb[0], x1 = xb[7500], x2 = xb[15000];
        a0+=x0; a1+=x1; a2+=x2;
        m00+=x0*x0; m01+=x0*x1; m02+=x0*x2; m11+=x1*x1; m12+=x1*x2; m22+=x2*x2;
    }
    a0=waveRed(a0); a1=waveRed(a1); a2=waveRed(a2);
    m00=waveRed(m00); m01=waveRed(m01); m02=waveRed(m02);
    m11=waveRed(m11); m12=waveRed(m12); m22=waveRed(m22);
    if ((threadIdx.x & 63) == 0) {
        atomicAdd(&ws[WS_XSUM+0],a0); atomicAdd(&ws[WS_XSUM+1],a1); atomicAdd(&ws[WS_XSUM+2],a2);
        atomicAdd(&ws[WS_XSS+0],m00); atomicAdd(&ws[WS_XSS+1],m01); atomicAdd(&ws[WS_XSS+2],m02);
        atomicAdd(&ws[WS_XSS+3],m11); atomicAdd(&ws[WS_XSS+4],m12); atomicAdd(&ws[WS_XSS+5],m22);
    }
}

// ---------------- sw[c,m] = sum_l weight^2 ----------------
__global__ void k_prepw(const float* __restrict__ weight, float* __restrict__ ws) {
    int idx = blockIdx.x * blockDim.x + threadIdx.x;
    if (idx < 2500) {
        float s = 0;
        #pragma unroll
        for (int l = 0; l < NTL; l++) { float w = weight[idx*NTL + l]; s += w*w; }
        ws[WS_SW + idx] = s;
    }
}

// ---------------- W1 transpose: W1T[c][o] = w1[o][c] ----------------
__global__ void k_prepw1t(const float* __restrict__ w1g, float* __restrict__ ws) {
    int idx = blockIdx.x * 256 + threadIdx.x;
    if (idx < 8192) {
        int c = idx >> 7, o = idx & 127;
        ws[WS_W1T + idx] = w1g[o*64 + c];
    }
}

// ---------------- BN0 folded affine from x moments (exact linearity) ----------------
__global__ void k_prep0(const float* __restrict__ w, const float* __restrict__ bb,
                        const float* __restrict__ g, const float* __restrict__ bt,
                        float* __restrict__ ws) {
    int o = threadIdx.x; // 64
    float inv = 1.0f / (float)N_POS;
    float mx0 = ws[WS_XSUM+0]*inv, mx1 = ws[WS_XSUM+1]*inv, mx2 = ws[WS_XSUM+2]*inv;
    float C00 = ws[WS_XSS+0]*inv - mx0*mx0;
    float C01 = ws[WS_XSS+1]*inv - mx0*mx1;
    float C02 = ws[WS_XSS+2]*inv - mx0*mx2;
    float C11 = ws[WS_XSS+3]*inv - mx1*mx1;
    float C12 = ws[WS_XSS+4]*inv - mx1*mx2;
    float C22 = ws[WS_XSS+5]*inv - mx2*mx2;
    float w0 = w[o*3], w1 = w[o*3+1], w2 = w[o*3+2];
    float mu  = w0*mx0 + w1*mx1 + w2*mx2 + bb[o];
    float var = w0*w0*C00 + w1*w1*C11 + w2*w2*C22
              + 2.f*(w0*w1*C01 + w0*w2*C02 + w1*w2*C12);
    float sc = g[o] / sqrtf(var + 1e-5f);
    float sh = bt[o] - sc*mu;
    ws[WS_WA + o*4 + 0] = sc*w0;
    ws[WS_WA + o*4 + 1] = sc*w1;
    ws[WS_WA + o*4 + 2] = sc*w2;
    ws[WS_WA + o*4 + 3] = sc*bb[o] + sh;
}

// ---------------- z1 GEMM pass (LDS-tiled, 4pos x 8out register tiles) ----
#define ZP_BLOCKS 500
#define ZP_CHUNKS 15
template<int MODE>
__global__ __launch_bounds__(256) void k_zpass(
        const float* __restrict__ x,
        const float* __restrict__ b1g,
        const float* __restrict__ w2g,
        const float* __restrict__ b2g,
        float* __restrict__ ws) {
    __shared__ float smem[12544];         // 50176 B
    float* s_h0  = smem;                  // [64 ch][68 pos-pad]
    float* s_w1t = smem + 4352;           // [64 c][128 o]
    int tid = threadIdx.x;

    for (int i = tid; i < 8192; i += 256) s_w1t[i] = ws[WS_W1T + i];

    int pos = tid & 63, cset = tid >> 6;  // staging mapping
    int pg  = tid >> 4, og  = tid & 15;   // GEMM mapping

    float b1r[8];
    #pragma unroll
    for (int o = 0; o < 8; o++) b1r[o] = b1g[og*8 + o];
    float sc1r[8], sh1r[8], w2r[8], b2v = 0.f;
    if constexpr (MODE == 1) {
        #pragma unroll
        for (int o = 0; o < 8; o++) {
            sc1r[o] = ws[WS_SC1 + og*8 + o];
            sh1r[o] = ws[WS_SH1 + og*8 + o];
            w2r[o]  = w2g[og*8 + o];
        }
        b2v = b2g[0];
    }
    float zs[8], zq[8];
    #pragma unroll
    for (int o = 0; o < 8; o++) { zs[o] = 0.f; zq[o] = 0.f; }
    float z2s = 0.f, z2q = 0.f;

    __syncthreads();

    for (int ci = 0; ci < ZP_CHUNKS; ci++) {
        int chunk = blockIdx.x * ZP_CHUNKS + ci;
        int P = chunk*64 + pos;
        int b = P / 7500, rem = P - b*7500;
        const float* xb = x + b*22500 + rem;
        float x0 = xb[0], x1 = xb[7500], x2 = xb[15000];
        #pragma unroll
        for (int k = 0; k < 16; k++) {
            int ch = cset*16 + k;
            const float4 wa = *(const float4*)&ws[WS_WA + ch*4];
            s_h0[ch*68 + pos] = fmaxf(wa.x*x0 + wa.y*x1 + wa.z*x2 + wa.w, 0.f);
        }
        __syncthreads();

        float acc[4][8];
        #pragma unroll
        for (int p = 0; p < 4; p++)
            #pragma unroll
            for (int o = 0; o < 8; o++) acc[p][o] = 0.f;

        #pragma unroll 4
        for (int c = 0; c < 64; c++) {
            float4 ha = *(const float4*)&s_h0[c*68 + 4*pg];
            float4 wl = *(const float4*)&s_w1t[c*128 + 8*og];
            float4 wh = *(const float4*)&s_w1t[c*128 + 8*og + 4];
            #pragma unroll
            for (int p = 0; p < 4; p++) {
                float hv = ((const float*)&ha)[p];
                #pragma unroll
                for (int o = 0; o < 4; o++) {
                    acc[p][o]   = fmaf(hv, ((const float*)&wl)[o], acc[p][o]);
                    acc[p][o+4] = fmaf(hv, ((const float*)&wh)[o], acc[p][o+4]);
                }
            }
        }

        if constexpr (MODE == 0) {
            #pragma unroll
            for (int o = 0; o < 8; o++) {
                #pragma unroll
                for (int p = 0; p < 4; p++) {
                    float z = acc[p][o] + b1r[o];
                    zs[o] += z; zq[o] += z*z;
                }
            }
            __syncthreads();   // protect s_h0 before next staging
        } else {
            float zp[4];
            #pragma unroll
            for (int p = 0; p < 4; p++) {
                float s = 0.f;
                #pragma unroll
                for (int o = 0; o < 8; o++) {
                    float z = acc[p][o] + b1r[o];
                    s += w2r[o]*fmaxf(sc1r[o]*z + sh1r[o], 0.f);
                }
                zp[p] = s;
            }
            __syncthreads();               // all GEMM reads of s_h0 done
            float* s_z2p = smem;           // [64 pos][17]
            #pragma unroll
            for (int p = 0; p < 4; p++) s_z2p[(4*pg + p)*17 + og] = zp[p];
            __syncthreads();
            if (tid < 64) {
                float z2 = b2v;
                #pragma unroll
                for (int j = 0; j < 16; j++) z2 += s_z2p[tid*17 + j];
                ws[WS_Z2 + chunk*64 + tid] = z2;
                z2s += z2; z2q += z2*z2;
            }
            __syncthreads();               // protect overlay before next staging
        }
    }

    if constexpr (MODE == 0) {
        float* s_part = smem;              // [128 o][17]
        #pragma unroll
        for (int o = 0; o < 8; o++) s_part[(og*8 + o)*17 + pg] = zs[o];
        __syncthreads();
        if (tid < 128) {
            float s = 0.f;
            #pragma unroll
            for (int j = 0; j < 16; j++) s += s_part[tid*17 + j];
            atomicAdd(&ws[WS_Z1SUM + tid], s);
        }
        __syncthreads();
        #pragma unroll
        for (int o = 0; o < 8; o++) s_part[(og*8 + o)*17 + pg] = zq[o];
        __syncthreads();
        if (tid < 128) {
            float s = 0.f;
            #pragma unroll
            for (int j = 0; j < 16; j++) s += s_part[tid*17 + j];
            atomicAdd(&ws[WS_Z1SQ + tid], s);
        }
    } else {
        if (tid < 64) {
            z2s = waveRed(z2s);
            z2q = waveRed(z2q);
            if (tid == 0) { atomicAdd(&ws[WS_Z2SUM], z2s); atomicAdd(&ws[WS_Z2SQ], z2q); }
        }
    }
}

__global__ void k_prep1(const float* __restrict__ g, const float* __restrict__ bt,
                        float* __restrict__ ws) {
    int o = threadIdx.x; // 128
    float inv = 1.0f / (float)N_POS;
    float m = ws[WS_Z1SUM+o]*inv;
    float v = ws[WS_Z1SQ+o]*inv - m*m;
    float sc = g[o] / sqrtf(v + 1e-5f);
    ws[WS_SC1+o] = sc;
    ws[WS_SH1+o] = bt[o] - sc*m;
}

__global__ void k_prep2(const float* __restrict__ g, const float* __restrict__ bt,
                        float* __restrict__ ws) {
    float inv = 1.0f / (float)N_POS;
    float m = ws[WS_Z2SUM]*inv;
    float v = ws[WS_Z2SQ]*inv - m*m;
    float sc = g[0] / sqrtf(v + 1e-5f);
    ws[WS_SC2] = sc;
    ws[WS_SH2] = bt[0] - sc*m;
}

// ---------------- x_series (b,v,t) + per-(b,v) t-mean ----------------
__global__ void k_xs(float* __restrict__ ws) {
    __shared__ float red[128];
    int bid = blockIdx.x;       // b*25+v
    int b = bid / 25, v = bid - b*25;
    float sc = ws[WS_SC2], sh = ws[WS_SH2];
    float local = 0.f;
    for (int t = threadIdx.x; t < NT; t += 128) {
        float val = fmaxf(sc * ws[WS_Z2 + b*7500 + t*25 + v] + sh, 0.f);
        ws[WS_XS + (size_t)bid*NT + t] = val;
        local += val;
    }
    red[threadIdx.x] = local;
    __syncthreads();
    for (int s = 64; s > 0; s >>= 1) {
        if (threadIdx.x < s) red[threadIdx.x] += red[threadIdx.x + s];
        __syncthreads();
    }
    if (threadIdx.x == 0) ws[WS_HM + bid] = red[0] * (1.f/300.f);
}

// ---------------- cm[b,c,i,j] = tanh(x1[b,c,i]-x2[b,c,j]) ----------------
__global__ void k_cm(const float* __restrict__ c1w, const float* __restrict__ c1b,
                     const float* __restrict__ c2w, const float* __restrict__ c2b,
                     float* __restrict__ ws) {
    __shared__ float s_hm[25];
    int bid = blockIdx.x;       // b*100+c
    int b = bid / 100, c = bid - b*100;
    if (threadIdx.x < 25) s_hm[threadIdx.x] = ws[WS_HM + b*25 + threadIdx.x];
    float a1 = c1w[c], d1 = c1b[c], a2 = c2w[c], d2 = c2b[c];
    __syncthreads();
    for (int idx = threadIdx.x; idx < 625; idx += 256) {
        int i = idx / 25, j = idx - i*25;
        ws[WS_CM + (size_t)bid*625 + idx] = tanhf(a1*s_hm[i] + d1 - a2*s_hm[j] - d2);
    }
}

// ---------------- GCs ----------------
__global__ void k_gcs(const float* __restrict__ ws, float* __restrict__ out) {
    int gid = blockIdx.x * 256 + threadIdx.x;
    if (gid < 40000) {
        int b = gid / 625; int rem = gid - b*625; int m = rem % 25;
        float acc = 0.f;
        for (int c = 0; c < 100; c++) {
            float v = ws[WS_CM + ((size_t)(b*100+c))*625 + rem];
            acc += v*v*ws[WS_SW + c*25 + m];
        }
        out[gid] = sqrtf(acc);
    }
}

// ---------------- panelty ----------------
__global__ void k_pan(float* __restrict__ ws) {
    __shared__ float s_colsq[25];
    __shared__ float s_n1, s_r;
    int tid = threadIdx.x;
    int b = blockIdx.x;
    if (tid < 25) s_colsq[tid] = 0.f;
    if (tid == 0) { s_n1 = 0.f; s_r = 0.f; }
    __syncthreads();
    float ln1 = 0.f;
    for (int idx = tid; idx < 625; idx += 256) {
        int j = idx % 25;
        float sq = 0.f;
        for (int c = 0; c < 100; c++) {
            float v = ws[WS_CM + ((size_t)(b*100+c))*625 + idx];
            sq += v*v;
        }
        ln1 += sqrtf(sq);
        atomicAdd(&s_colsq[j], sq);
    }
    ln1 = waveRed(ln1);
    if ((tid & 63) == 0) atomicAdd(&s_n1, ln1);
    __syncthreads();
    if (tid < 25) atomicAdd(&s_r, sqrtf(s_colsq[tid]));
    __syncthreads();
    if (tid == 0) atomicAdd(&ws[WS_PAN], s_n1 + s_r);
}

// ---------------- regularize ----------------
__global__ void k_reg(const float* __restrict__ f0w, const float* __restrict__ f1w,
                      const float* __restrict__ f2w, float* __restrict__ ws) {
    int tid = blockIdx.x * blockDim.x + threadIdx.x;
    int nth = gridDim.x * blockDim.x;
    float a = 0.f;
    for (int i = tid; i < 275250; i += nth) {
        float w;
        if (i < 250000) w = f0w[i];
        else if (i < 275000) w = f1w[i - 250000];
        else w = f2w[i - 275000];
        a += w*w;
    }
    a = waveRed(a);
    if ((threadIdx.x & 63) == 0) atomicAdd(&ws[WS_REG], a);
}

// ---------------- Fc + p per (b,c), register-tiled, t-split halves ----------
// half 0: t in [0,148); half 1: t in [148,292) (len 144)
#define XP 156   // xs row pad (needs up to 156 elems)
#define FP 152   // fc row pad (tail b128 reads up to idx 151)
__global__ __launch_bounds__(256) void k_fcp(
        const float* __restrict__ weight, const float* __restrict__ wnorm,
        __hip_bfloat16* __restrict__ pbuf, const float* __restrict__ ws, int b_base) {
    __shared__ float s_xs[25*XP];   // 3900
    __shared__ float s_fc[25*FP];   // 3800
    __shared__ float s_wn[225];
    __shared__ float s_cm[625];
    int tid = threadIdx.x;
    int bid = blockIdx.x;
    int bl = bid / 100, c = bid - bl*100;
    int b = b_base + bl;

    for (int i = tid; i < 225; i += 256) s_wn[i] = weight[c*225 + i] / wnorm[i];
    for (int i = tid; i < 625; i += 256) s_cm[i] = ws[WS_CM + ((size_t)(b*100+c))*625 + i];

    #pragma unroll
    for (int h = 0; h < 2; h++) {
        const int t_base = h ? 148 : 0;
        const int TH     = h ? 144 : 148;   // half length
        const int NTQ4   = TH / 4;          // fc tiles per row (37 / 36, exact)
        const int NPV    = ((TH + 7) / 8);  // pv t-tiles (19 / 18)

        // stage xs rows [v][0..TH+8)
        for (int i = tid; i < 25*XP; i += 256) {
            int v = i / XP, u = i - v*XP;
            if (u < TH + 8) s_xs[i] = ws[WS_XS + (size_t)(b*25+v)*NT + t_base + u];
        }
        __syncthreads();

        // fc: task = v*NTQ4 + tq, 4 t's per task
        for (int task = tid; task < 25*NTQ4; task += 256) {
            int v = task / NTQ4, tq = task - v*NTQ4;
            int t0 = tq*4;
            float4 xa = *(const float4*)&s_xs[v*XP + t0];
            float4 xb = *(const float4*)&s_xs[v*XP + t0 + 4];
            float4 xc = *(const float4*)&s_xs[v*XP + t0 + 8];
            float xr[12];
            xr[0]=xa.x; xr[1]=xa.y; xr[2]=xa.z; xr[3]=xa.w;
            xr[4]=xb.x; xr[5]=xb.y; xr[6]=xb.z; xr[7]=xb.w;
            xr[8]=xc.x; xr[9]=xc.y; xr[10]=xc.z; xr[11]=xc.w;
            float f[4];
            #pragma unroll
            for (int k = 0; k < 4; k++) f[k] = 0.f;
            #pragma unroll
            for (int l = 0; l < NTL; l++) {
                float w = s_wn[v*NTL + l];
                #pragma unroll
                for (int k = 0; k < 4; k++) f[k] = fmaf(xr[k + l], w, f[k]);
            }
            *(float4*)&s_fc[v*FP + t0] = make_float4(f[0], f[1], f[2], f[3]);
        }
        __syncthreads();

        // PV: task = tq*25 + ii, 8 t's per task
        for (int task = tid; task < NPV*25; task += 256) {
            int tq = task / 25, ii = task - tq*25;
            int t0 = tq*8;
            float cmv[25];
            #pragma unroll
            for (int v = 0; v < 25; v++) cmv[v] = s_cm[v*25 + ii];
            float acc[8];
            #pragma unroll
            for (int k = 0; k < 8; k++) acc[k] = 0.f;
            #pragma unroll
            for (int v = 0; v < 25; v++) {
                float4 f0 = *(const float4*)&s_fc[v*FP + t0];
                float4 f1 = *(const float4*)&s_fc[v*FP + t0 + 4];
                float cv = cmv[v];
                acc[0] = fmaf(cv, f0.x, acc[0]);
                acc[1] = fmaf(cv, f0.y, acc[1]);
                acc[2] = fmaf(cv, f0.z, acc[2]);
                acc[3] = fmaf(cv, f0.w, acc[3]);
                acc[4] = fmaf(cv, f1.x, acc[4]);
                acc[5] = fmaf(cv, f1.y, acc[5]);
                acc[6] = fmaf(cv, f1.z, acc[6]);
                acc[7] = fmaf(cv, f1.w, acc[7]);
            }
            size_t row = (size_t)((bl*25 + ii)*100 + c);
            size_t gbase = row*NL + t_base + t0;
            unsigned p0 = pack2bf(acc[0], acc[1]);
            unsigned p1 = pack2bf(acc[2], acc[3]);
            if (t0 + 8 <= TH) {
                unsigned p2 = pack2bf(acc[4], acc[5]);
                unsigned p3 = pack2bf(acc[6], acc[7]);
                *reinterpret_cast<uint2*>(pbuf + gbase)     = make_uint2(p0, p1);
                *reinterpret_cast<uint2*>(pbuf + gbase + 4) = make_uint2(p2, p3);
            } else {
                // tail (only h=0, tq=18: 4 valid t's)
                *reinterpret_cast<uint2*>(pbuf + gbase) = make_uint2(p0, p1);
            }
        }
        __syncthreads();
    }
}

// ---------------- group MLP f0/f1/f2 + loss (balanced, reg-resident) -------
// block = (g, chunk of 256 (bl,t)-tasks); tasks per g = nb*292.
__global__ __launch_bounds__(256, 1) void k_mlp(
        const __hip_bfloat16* __restrict__ pbuf,
        const float* __restrict__ f0w, const float* __restrict__ f0b,
        const float* __restrict__ f1w, const float* __restrict__ f1b,
        const float* __restrict__ f2w, const float* __restrict__ f2b,
        float* __restrict__ ws, int b_base, int nb, int nchunks) {
    __shared__ float s_w1t[1000];   // [o][o2]
    __shared__ float s_loss;
    int tid = threadIdx.x;
    int g     = blockIdx.x / nchunks;
    int chunk = blockIdx.x - g*nchunks;
    for (int i = tid; i < 1000; i += 256) {
        int o = i / 10, o2 = i - o*10;
        s_w1t[i] = f1w[g*1000 + o2*100 + o];
    }
    if (tid == 0) s_loss = 0.f;
    __syncthreads();

    const float* w0 = f0w + g*10000;
    const float* b0 = f0b + g*100;
    const float* b1 = f1b + g*10;
    const float* w2 = f2w + g*10;
    float b2 = f2b[g];

    float local = 0.f;
    int tau = chunk*256 + tid;
    if (tau < nb*292) {
        int bl = tau / 292, t = tau - bl*292;
        const __hip_bfloat16* pg = pbuf + ((size_t)(bl*25 + g))*100*NL + t;
        float pr[100];
        #pragma unroll
        for (int cc = 0; cc < 100; cc++) pr[cc] = __bfloat162float(pg[(size_t)cc*NL]);
        float acc2[10];
        #pragma unroll
        for (int o2 = 0; o2 < 10; o2++) acc2[o2] = b1[o2];
        for (int o = 0; o < 100; o += 2) {
            float a  = b0[o];
            float aa = b0[o+1];
            const float* wr  = w0 + o*100;
            const float* wr2 = wr + 100;
            #pragma unroll
            for (int cc = 0; cc < 100; cc++) {
                a  = fmaf(wr[cc],  pr[cc], a);
                aa = fmaf(wr2[cc], pr[cc], aa);
            }
            a  = fmaxf(a, 0.f);
            aa = fmaxf(aa, 0.f);
            #pragma unroll
            for (int o2 = 0; o2 < 10; o2++) {
                acc2[o2] = fmaf(s_w1t[o*10 + o2],     a,  acc2[o2]);
                acc2[o2] = fmaf(s_w1t[(o+1)*10 + o2], aa, acc2[o2]);
            }
        }
        float z3 = b2;
        #pragma unroll
        for (int o2 = 0; o2 < 10; o2++) z3 += w2[o2]*fmaxf(acc2[o2], 0.f);
        z3 = fmaxf(z3, 0.f);
        if (t < NL-1) {
            int b = b_base + bl;
            float d = ws[WS_XS + ((size_t)(b*25 + g))*NT + t + NTL] - z3;
            local = d*d;
        }
    }
    local = waveRed(local);
    if ((tid & 63) == 0) atomicAdd(&s_loss, local);
    __syncthreads();
    if (tid == 0) atomicAdd(&ws[WS_LOSS], s_loss);
}

// ---------------- final scalars ----------------
__global__ void k_final(float* __restrict__ out, const float* __restrict__ ws) {
    out[40000] = ws[WS_LOSS] * (1.f / 465600.f);
    out[40001] = 1e-4f * ws[WS_PAN];
    out[40002] = 1e-4f * ws[WS_REG];
}

extern "C" void kernel_launch(void* const* d_in, const int* in_sizes, int n_in,
                              void* d_out, int out_size, void* d_ws, size_t ws_size,
                              hipStream_t stream) {
    const float* x      = (const float*)d_in[0];
    const float* weight = (const float*)d_in[1];
    const float* wnorm  = (const float*)d_in[2];
    const float* fb0_w  = (const float*)d_in[3];
    const float* fb0_b  = (const float*)d_in[4];
    const float* bn0_g  = (const float*)d_in[5];
    const float* bn0_b  = (const float*)d_in[6];
    const float* fb1_w  = (const float*)d_in[7];
    const float* fb1_b  = (const float*)d_in[8];
    const float* bn1_g  = (const float*)d_in[9];
    const float* bn1_b  = (const float*)d_in[10];
    const float* fb2_w  = (const float*)d_in[11];
    const float* fb2_b  = (const float*)d_in[12];
    const float* bn2_g  = (const float*)d_in[13];
    const float* bn2_b  = (const float*)d_in[14];
    const float* c1_w   = (const float*)d_in[15];
    const float* c1_b   = (const float*)d_in[16];
    const float* c2_w   = (const float*)d_in[17];
    const float* c2_b   = (const float*)d_in[18];
    const float* f0_w   = (const float*)d_in[19];
    const float* f0_b   = (const float*)d_in[20];
    const float* f1_w   = (const float*)d_in[21];
    const float* f1_b   = (const float*)d_in[22];
    const float* f2_w   = (const float*)d_in[23];
    const float* f2_b   = (const float*)d_in[24];

    float* ws  = (float*)d_ws;
    float* out = (float*)d_out;
    __hip_bfloat16* pbuf = (__hip_bfloat16*)(ws + WS_P);

    // zero accumulators (floats 0..659)
    hipMemsetAsync(d_ws, 0, 2640, stream);

    k_xstats<<<512, 256, 0, stream>>>(x, ws);
    k_prepw<<<10, 256, 0, stream>>>(weight, ws);
    k_prepw1t<<<32, 256, 0, stream>>>(fb1_w, ws);
    k_prep0<<<1, 64, 0, stream>>>(fb0_w, fb0_b, bn0_g, bn0_b, ws);
    k_zpass<0><<<ZP_BLOCKS, 256, 0, stream>>>(x, fb1_b, fb2_w, fb2_b, ws);
    k_prep1<<<1, 128, 0, stream>>>(bn1_g, bn1_b, ws);
    k_zpass<1><<<ZP_BLOCKS, 256, 0, stream>>>(x, fb1_b, fb2_w, fb2_b, ws);
    k_prep2<<<1, 1, 0, stream>>>(bn2_g, bn2_b, ws);
    k_xs<<<1600, 128, 0, stream>>>(ws);
    k_cm<<<6400, 256, 0, stream>>>(c1_w, c1_b, c2_w, c2_b, ws);
    k_gcs<<<157, 256, 0, stream>>>(ws, out);
    k_pan<<<64, 256, 0, stream>>>(ws);
    k_reg<<<256, 256, 0, stream>>>(f0_w, f1_w, f2_w, ws);

    // Adaptive b-chunking for the bf16 p buffer (deterministic in ws_size ->
    // identical work every call; graph-capture safe).
    const size_t p_bytes_per_b = (size_t)25*100*NL*sizeof(__hip_bfloat16); // 1.46 MB
    size_t fixed_bytes = (size_t)WS_P * sizeof(float);
    size_t avail = ws_size > fixed_bytes ? ws_size - fixed_bytes : 0;
    int bs = (int)(avail / p_bytes_per_b);
    if (bs > 64) bs = 64;
    if (bs < 1)  bs = 1;
    for (int b0 = 0; b0 < 64; b0 += bs) {
        int nb = (64 - b0) < bs ? (64 - b0) : bs;
        k_fcp<<<nb*100, 256, 0, stream>>>(weight, wnorm, pbuf, ws, b0);
        int nch = (nb*292 + 255) / 256;
        k_mlp<<<25*nch, 256, 0, stream>>>(pbuf, f0_w, f0_b, f1_w, f1_b,
                                          f2_w, f2_b, ws, b0, nb, nch);
    }
    k_final<<<1, 1, 0, stream>>>(out, ws);
}

// Round 9
// 773.185 us; speedup vs baseline: 1.7632x; 1.3277x over previous
//
#include <hip/hip_runtime.h>
#include <hip/hip_bf16.h>
#include <string.h>

// Problem constants
#define N_POS 480000      // B*T*V = 64*300*25
#define NB    64
#define NT    300
#define NV    25
#define NCC   100
#define NTL   9
#define NL    292         // T - TL + 1

// Workspace float offsets. Atomic targets live on PRIVATE 64B cache lines
// (stride-16 floats) -- same-line atomic RMWs serialize at ~31cyc/op (R7).
#define WS_XA     0       // 9 accumulators at stride 16 (0,16,...,128)
#define WS_Z2SUM  144
#define WS_Z2SQ   160
#define WS_LOSS   176
#define WS_PAN    192
#define WS_REG    208
#define WS_SC1    224     // 128
#define WS_SH1    352     // 128
#define WS_SC2    480
#define WS_SH2    481
#define WS_WA     512     // 256: packed (sc*w0, sc*w1, sc*w2, ba) per ch
#define WS_W1T    768     // 8192: W1 transposed [c][o]
#define WS_SW     8960    // 2500 = sum_l weight^2 (100x25)
#define WS_HM     11460   // 1600 (B*V t-means)
#define WS_Z1P    13060   // 500*128 z1 sum partials
#define WS_Z1PQ   77060   // 500*128 z1 sumsq partials
#define WS_Z2     141060  // 480000 (b,t,v)
#define WS_XS     621060  // 480000 (b,v,t)
#define WS_CM     1101060 // 4,000,000 (b,c,i,j)
#define WS_P      5101060 // bf16 p buffer starts here

__device__ __forceinline__ float waveRed(float v) {
    #pragma unroll
    for (int off = 32; off > 0; off >>= 1) v += __shfl_down(v, off);
    return v;
}

__device__ __forceinline__ unsigned pack2bf(float a, float b) {
    __hip_bfloat16 ha = __float2bfloat16(a), hb = __float2bfloat16(b);
    unsigned short ua, ub;
    memcpy(&ua, &ha, 2); memcpy(&ub, &hb, 2);
    return (unsigned)ua | ((unsigned)ub << 16);
}

// ---------------- Pass A: x channel stats (float4, block-reduced) ----------
__global__ __launch_bounds__(256) void k_xstats(const float* __restrict__ x,
                                                float* __restrict__ ws) {
    __shared__ float s_red[4][9];
    int tid = blockIdx.x * 256 + threadIdx.x;
    int nth = gridDim.x * 256;
    float a[9];
    #pragma unroll
    for (int i = 0; i < 9; i++) a[i] = 0.f;
    // 120000 tasks = 64 b * 1875 float4-quads per channel row
    for (int task = tid; task < 120000; task += nth) {
        int b = task / 1875; int q = task - b*1875;
        const float* xb = x + b*22500 + q*4;
        float4 v0 = *(const float4*)(xb);
        float4 v1 = *(const float4*)(xb + 7500);
        float4 v2 = *(const float4*)(xb + 15000);
        const float* p0 = (const float*)&v0;
        const float* p1 = (const float*)&v1;
        const float* p2 = (const float*)&v2;
        #pragma unroll
        for (int k = 0; k < 4; k++) {
            float x0 = p0[k], x1 = p1[k], x2 = p2[k];
            a[0] += x0; a[1] += x1; a[2] += x2;
            a[3] = fmaf(x0,x0,a[3]); a[4] = fmaf(x0,x1,a[4]); a[5] = fmaf(x0,x2,a[5]);
            a[6] = fmaf(x1,x1,a[6]); a[7] = fmaf(x1,x2,a[7]); a[8] = fmaf(x2,x2,a[8]);
        }
    }
    #pragma unroll
    for (int i = 0; i < 9; i++) a[i] = waveRed(a[i]);
    int w = threadIdx.x >> 6;
    if ((threadIdx.x & 63) == 0) {
        #pragma unroll
        for (int i = 0; i < 9; i++) s_red[w][i] = a[i];
    }
    __syncthreads();
    if (threadIdx.x < 9) {
        float s = s_red[0][threadIdx.x] + s_red[1][threadIdx.x]
                + s_red[2][threadIdx.x] + s_red[3][threadIdx.x];
        atomicAdd(&ws[WS_XA + threadIdx.x*16], s);
    }
}

// ---------------- sw[c,m] = sum_l weight^2 ----------------
__global__ void k_prepw(const float* __restrict__ weight, float* __restrict__ ws) {
    int idx = blockIdx.x * blockDim.x + threadIdx.x;
    if (idx < 2500) {
        float s = 0;
        #pragma unroll
        for (int l = 0; l < NTL; l++) { float w = weight[idx*NTL + l]; s += w*w; }
        ws[WS_SW + idx] = s;
    }
}

// ---------------- W1 transpose: W1T[c][o] = w1[o][c] ----------------
__global__ void k_prepw1t(const float* __restrict__ w1g, float* __restrict__ ws) {
    int idx = blockIdx.x * 256 + threadIdx.x;
    if (idx < 8192) {
        int c = idx >> 7, o = idx & 127;
        ws[WS_W1T + idx] = w1g[o*64 + c];
    }
}

// ---------------- BN0 folded affine from x moments (exact linearity) -------
__global__ void k_prep0(const float* __restrict__ w, const float* __restrict__ bb,
                        const float* __restrict__ g, const float* __restrict__ bt,
                        float* __restrict__ ws) {
    int o = threadIdx.x; // 64
    float inv = 1.0f / (float)N_POS;
    float mx0 = ws[WS_XA+0]*inv, mx1 = ws[WS_XA+16]*inv, mx2 = ws[WS_XA+32]*inv;
    float C00 = ws[WS_XA+48]*inv  - mx0*mx0;
    float C01 = ws[WS_XA+64]*inv  - mx0*mx1;
    float C02 = ws[WS_XA+80]*inv  - mx0*mx2;
    float C11 = ws[WS_XA+96]*inv  - mx1*mx1;
    float C12 = ws[WS_XA+112]*inv - mx1*mx2;
    float C22 = ws[WS_XA+128]*inv - mx2*mx2;
    float w0 = w[o*3], w1 = w[o*3+1], w2 = w[o*3+2];
    float mu  = w0*mx0 + w1*mx1 + w2*mx2 + bb[o];
    float var = w0*w0*C00 + w1*w1*C11 + w2*w2*C22
              + 2.f*(w0*w1*C01 + w0*w2*C02 + w1*w2*C12);
    float sc = g[o] / sqrtf(var + 1e-5f);
    float sh = bt[o] - sc*mu;
    ws[WS_WA + o*4 + 0] = sc*w0;
    ws[WS_WA + o*4 + 1] = sc*w1;
    ws[WS_WA + o*4 + 2] = sc*w2;
    ws[WS_WA + o*4 + 3] = sc*bb[o] + sh;
}

// ---------------- z1 GEMM pass (LDS-tiled, 4pos x 8out register tiles) ----
#define ZP_BLOCKS 500
#define ZP_CHUNKS 15
template<int MODE>
__global__ __launch_bounds__(256) void k_zpass(
        const float* __restrict__ x,
        const float* __restrict__ b1g,
        const float* __restrict__ w2g,
        const float* __restrict__ b2g,
        float* __restrict__ ws) {
    __shared__ float smem[12544];         // 50176 B
    float* s_h0  = smem;                  // [64 ch][68 pos-pad]
    float* s_w1t = smem + 4352;           // [64 c][128 o]
    int tid = threadIdx.x;

    for (int i = tid; i < 8192; i += 256) s_w1t[i] = ws[WS_W1T + i];

    int pos = tid & 63, cset = tid >> 6;  // staging mapping
    int pg  = tid >> 4, og  = tid & 15;   // GEMM mapping

    float b1r[8];
    #pragma unroll
    for (int o = 0; o < 8; o++) b1r[o] = b1g[og*8 + o];
    float sc1r[8], sh1r[8], w2r[8], b2v = 0.f;
    if constexpr (MODE == 1) {
        #pragma unroll
        for (int o = 0; o < 8; o++) {
            sc1r[o] = ws[WS_SC1 + og*8 + o];
            sh1r[o] = ws[WS_SH1 + og*8 + o];
            w2r[o]  = w2g[og*8 + o];
        }
        b2v = b2g[0];
    }
    float zs[8], zq[8];
    #pragma unroll
    for (int o = 0; o < 8; o++) { zs[o] = 0.f; zq[o] = 0.f; }
    float z2s = 0.f, z2q = 0.f;

    __syncthreads();

    for (int ci = 0; ci < ZP_CHUNKS; ci++) {
        int chunk = blockIdx.x * ZP_CHUNKS + ci;
        int P = chunk*64 + pos;
        int b = P / 7500, rem = P - b*7500;
        const float* xb = x + b*22500 + rem;
        float x0 = xb[0], x1 = xb[7500], x2 = xb[15000];
        #pragma unroll
        for (int k = 0; k < 16; k++) {
            int ch = cset*16 + k;
            const float4 wa = *(const float4*)&ws[WS_WA + ch*4];
            s_h0[ch*68 + pos] = fmaxf(wa.x*x0 + wa.y*x1 + wa.z*x2 + wa.w, 0.f);
        }
        __syncthreads();

        float acc[4][8];
        #pragma unroll
        for (int p = 0; p < 4; p++)
            #pragma unroll
            for (int o = 0; o < 8; o++) acc[p][o] = 0.f;

        #pragma unroll 4
        for (int c = 0; c < 64; c++) {
            float4 ha = *(const float4*)&s_h0[c*68 + 4*pg];
            float4 wl = *(const float4*)&s_w1t[c*128 + 8*og];
            float4 wh = *(const float4*)&s_w1t[c*128 + 8*og + 4];
            #pragma unroll
            for (int p = 0; p < 4; p++) {
                float hv = ((const float*)&ha)[p];
                #pragma unroll
                for (int o = 0; o < 4; o++) {
                    acc[p][o]   = fmaf(hv, ((const float*)&wl)[o], acc[p][o]);
                    acc[p][o+4] = fmaf(hv, ((const float*)&wh)[o], acc[p][o+4]);
                }
            }
        }

        if constexpr (MODE == 0) {
            #pragma unroll
            for (int o = 0; o < 8; o++) {
                #pragma unroll
                for (int p = 0; p < 4; p++) {
                    float z = acc[p][o] + b1r[o];
                    zs[o] += z; zq[o] += z*z;
                }
            }
            __syncthreads();   // protect s_h0 before next staging
        } else {
            float zp[4];
            #pragma unroll
            for (int p = 0; p < 4; p++) {
                float s = 0.f;
                #pragma unroll
                for (int o = 0; o < 8; o++) {
                    float z = acc[p][o] + b1r[o];
                    s += w2r[o]*fmaxf(sc1r[o]*z + sh1r[o], 0.f);
                }
                zp[p] = s;
            }
            __syncthreads();               // all GEMM reads of s_h0 done
            float* s_z2p = smem;           // [64 pos][17]
            #pragma unroll
            for (int p = 0; p < 4; p++) s_z2p[(4*pg + p)*17 + og] = zp[p];
            __syncthreads();
            if (tid < 64) {
                float z2 = b2v;
                #pragma unroll
                for (int j = 0; j < 16; j++) z2 += s_z2p[tid*17 + j];
                ws[WS_Z2 + chunk*64 + tid] = z2;
                z2s += z2; z2q += z2*z2;
            }
            __syncthreads();               // protect overlay before next staging
        }
    }

    if constexpr (MODE == 0) {
        // block partials -> global arrays (NO atomics; reduced by k_z1red)
        float* s_part = smem;              // [128 o][17]
        #pragma unroll
        for (int o = 0; o < 8; o++) s_part[(og*8 + o)*17 + pg] = zs[o];
        __syncthreads();
        if (tid < 128) {
            float s = 0.f;
            #pragma unroll
            for (int j = 0; j < 16; j++) s += s_part[tid*17 + j];
            ws[WS_Z1P + blockIdx.x*128 + tid] = s;
        }
        __syncthreads();
        #pragma unroll
        for (int o = 0; o < 8; o++) s_part[(og*8 + o)*17 + pg] = zq[o];
        __syncthreads();
        if (tid < 128) {
            float s = 0.f;
            #pragma unroll
            for (int j = 0; j < 16; j++) s += s_part[tid*17 + j];
            ws[WS_Z1PQ + blockIdx.x*128 + tid] = s;
        }
    } else {
        if (tid < 64) {
            z2s = waveRed(z2s);
            z2q = waveRed(z2q);
            if (tid == 0) { atomicAdd(&ws[WS_Z2SUM], z2s); atomicAdd(&ws[WS_Z2SQ], z2q); }
        }
    }
}

// ---------------- reduce z1 partials -> BN1 affine (replaces k_prep1) ------
__global__ __launch_bounds__(256) void k_z1red(const float* __restrict__ g,
                                               const float* __restrict__ bt,
                                               float* __restrict__ ws) {
    __shared__ float ss[4], qq[4];
    int o = blockIdx.x;  // 0..127
    float s = 0.f, q = 0.f;
    for (int blk = threadIdx.x; blk < ZP_BLOCKS; blk += 256) {
        s += ws[WS_Z1P  + blk*128 + o];
        q += ws[WS_Z1PQ + blk*128 + o];
    }
    s = waveRed(s); q = waveRed(q);
    int w = threadIdx.x >> 6;
    if ((threadIdx.x & 63) == 0) { ss[w] = s; qq[w] = q; }
    __syncthreads();
    if (threadIdx.x == 0) {
        float S = ss[0]+ss[1]+ss[2]+ss[3];
        float Q = qq[0]+qq[1]+qq[2]+qq[3];
        float inv = 1.0f / (float)N_POS;
        float m = S*inv;
        float v = Q*inv - m*m;
        float sc = g[o] / sqrtf(v + 1e-5f);
        ws[WS_SC1+o] = sc;
        ws[WS_SH1+o] = bt[o] - sc*m;
    }
}

__global__ void k_prep2(const float* __restrict__ g, const float* __restrict__ bt,
                        float* __restrict__ ws) {
    float inv = 1.0f / (float)N_POS;
    float m = ws[WS_Z2SUM]*inv;
    float v = ws[WS_Z2SQ]*inv - m*m;
    float sc = g[0] / sqrtf(v + 1e-5f);
    ws[WS_SC2] = sc;
    ws[WS_SH2] = bt[0] - sc*m;
}

// ---------------- x_series (b,v,t) + per-(b,v) t-mean ----------------
__global__ void k_xs(float* __restrict__ ws) {
    __shared__ float red[128];
    int bid = blockIdx.x;       // b*25+v
    int b = bid / 25, v = bid - b*25;
    float sc = ws[WS_SC2], sh = ws[WS_SH2];
    float local = 0.f;
    for (int t = threadIdx.x; t < NT; t += 128) {
        float val = fmaxf(sc * ws[WS_Z2 + b*7500 + t*25 + v] + sh, 0.f);
        ws[WS_XS + (size_t)bid*NT + t] = val;
        local += val;
    }
    red[threadIdx.x] = local;
    __syncthreads();
    for (int s = 64; s > 0; s >>= 1) {
        if (threadIdx.x < s) red[threadIdx.x] += red[threadIdx.x + s];
        __syncthreads();
    }
    if (threadIdx.x == 0) ws[WS_HM + bid] = red[0] * (1.f/300.f);
}

// ---------------- cm[b,c,i,j] = tanh(x1[b,c,i]-x2[b,c,j]) ----------------
__global__ void k_cm(const float* __restrict__ c1w, const float* __restrict__ c1b,
                     const float* __restrict__ c2w, const float* __restrict__ c2b,
                     float* __restrict__ ws) {
    __shared__ float s_hm[25];
    int bid = blockIdx.x;       // b*100+c
    int b = bid / 100, c = bid - b*100;
    if (threadIdx.x < 25) s_hm[threadIdx.x] = ws[WS_HM + b*25 + threadIdx.x];
    float a1 = c1w[c], d1 = c1b[c], a2 = c2w[c], d2 = c2b[c];
    __syncthreads();
    for (int idx = threadIdx.x; idx < 625; idx += 256) {
        int i = idx / 25, j = idx - i*25;
        ws[WS_CM + (size_t)bid*625 + idx] = tanhf(a1*s_hm[i] + d1 - a2*s_hm[j] - d2);
    }
}

// ---------------- GCs ----------------
__global__ void k_gcs(const float* __restrict__ ws, float* __restrict__ out) {
    int gid = blockIdx.x * 256 + threadIdx.x;
    if (gid < 40000) {
        int b = gid / 625; int rem = gid - b*625; int m = rem % 25;
        float acc = 0.f;
        for (int c = 0; c < 100; c++) {
            float v = ws[WS_CM + ((size_t)(b*100+c))*625 + rem];
            acc += v*v*ws[WS_SW + c*25 + m];
        }
        out[gid] = sqrtf(acc);
    }
}

// ---------------- panelty ----------------
__global__ void k_pan(float* __restrict__ ws) {
    __shared__ float s_colsq[25];
    __shared__ float s_n1, s_r;
    int tid = threadIdx.x;
    int b = blockIdx.x;
    if (tid < 25) s_colsq[tid] = 0.f;
    if (tid == 0) { s_n1 = 0.f; s_r = 0.f; }
    __syncthreads();
    float ln1 = 0.f;
    for (int idx = tid; idx < 625; idx += 256) {
        int j = idx % 25;
        float sq = 0.f;
        for (int c = 0; c < 100; c++) {
            float v = ws[WS_CM + ((size_t)(b*100+c))*625 + idx];
            sq += v*v;
        }
        ln1 += sqrtf(sq);
        atomicAdd(&s_colsq[j], sq);
    }
    ln1 = waveRed(ln1);
    if ((tid & 63) == 0) atomicAdd(&s_n1, ln1);
    __syncthreads();
    if (tid < 25) atomicAdd(&s_r, sqrtf(s_colsq[tid]));
    __syncthreads();
    if (tid == 0) atomicAdd(&ws[WS_PAN], s_n1 + s_r);
}

// ---------------- regularize ----------------
__global__ void k_reg(const float* __restrict__ f0w, const float* __restrict__ f1w,
                      const float* __restrict__ f2w, float* __restrict__ ws) {
    __shared__ float sred[4];
    int tid = blockIdx.x * blockDim.x + threadIdx.x;
    int nth = gridDim.x * blockDim.x;
    float a = 0.f;
    for (int i = tid; i < 275250; i += nth) {
        float w;
        if (i < 250000) w = f0w[i];
        else if (i < 275000) w = f1w[i - 250000];
        else w = f2w[i - 275000];
        a += w*w;
    }
    a = waveRed(a);
    int w = threadIdx.x >> 6;
    if ((threadIdx.x & 63) == 0) sred[w] = a;
    __syncthreads();
    if (threadIdx.x == 0)
        atomicAdd(&ws[WS_REG], sred[0]+sred[1]+sred[2]+sred[3]);
}

// ---------------- Fc + p per (b,c), register-tiled, t-split halves ----------
// half 0: t in [0,148); half 1: t in [148,292) (len 144)
#define XP 156   // xs row pad (needs up to 156 elems)
#define FP 152   // fc row pad (tail b128 reads up to idx 151)
__global__ __launch_bounds__(256) void k_fcp(
        const float* __restrict__ weight, const float* __restrict__ wnorm,
        __hip_bfloat16* __restrict__ pbuf, const float* __restrict__ ws, int b_base) {
    __shared__ float s_xs[25*XP];   // 3900
    __shared__ float s_fc[25*FP];   // 3800
    __shared__ float s_wn[225];
    __shared__ float s_cm[625];
    int tid = threadIdx.x;
    int bid = blockIdx.x;
    int bl = bid / 100, c = bid - bl*100;
    int b = b_base + bl;

    for (int i = tid; i < 225; i += 256) s_wn[i] = weight[c*225 + i] / wnorm[i];
    for (int i = tid; i < 625; i += 256) s_cm[i] = ws[WS_CM + ((size_t)(b*100+c))*625 + i];

    #pragma unroll
    for (int h = 0; h < 2; h++) {
        const int t_base = h ? 148 : 0;
        const int TH     = h ? 144 : 148;   // half length
        const int NTQ4   = TH / 4;          // fc tiles per row (37 / 36, exact)
        const int NPV    = ((TH + 7) / 8);  // pv t-tiles (19 / 18)

        // stage xs rows [v][0..TH+8)
        for (int i = tid; i < 25*XP; i += 256) {
            int v = i / XP, u = i - v*XP;
            if (u < TH + 8) s_xs[i] = ws[WS_XS + (size_t)(b*25+v)*NT + t_base + u];
        }
        __syncthreads();

        // fc: task = v*NTQ4 + tq, 4 t's per task
        for (int task = tid; task < 25*NTQ4; task += 256) {
            int v = task / NTQ4, tq = task - v*NTQ4;
            int t0 = tq*4;
            float4 xa = *(const float4*)&s_xs[v*XP + t0];
            float4 xb = *(const float4*)&s_xs[v*XP + t0 + 4];
            float4 xc = *(const float4*)&s_xs[v*XP + t0 + 8];
            float xr[12];
            xr[0]=xa.x; xr[1]=xa.y; xr[2]=xa.z; xr[3]=xa.w;
            xr[4]=xb.x; xr[5]=xb.y; xr[6]=xb.z; xr[7]=xb.w;
            xr[8]=xc.x; xr[9]=xc.y; xr[10]=xc.z; xr[11]=xc.w;
            float f[4];
            #pragma unroll
            for (int k = 0; k < 4; k++) f[k] = 0.f;
            #pragma unroll
            for (int l = 0; l < NTL; l++) {
                float w = s_wn[v*NTL + l];
                #pragma unroll
                for (int k = 0; k < 4; k++) f[k] = fmaf(xr[k + l], w, f[k]);
            }
            *(float4*)&s_fc[v*FP + t0] = make_float4(f[0], f[1], f[2], f[3]);
        }
        __syncthreads();

        // PV: task = tq*25 + ii, 8 t's per task
        for (int task = tid; task < NPV*25; task += 256) {
            int tq = task / 25, ii = task - tq*25;
            int t0 = tq*8;
            float cmv[25];
            #pragma unroll
            for (int v = 0; v < 25; v++) cmv[v] = s_cm[v*25 + ii];
            float acc[8];
            #pragma unroll
            for (int k = 0; k < 8; k++) acc[k] = 0.f;
            #pragma unroll
            for (int v = 0; v < 25; v++) {
                float4 f0 = *(const float4*)&s_fc[v*FP + t0];
                float4 f1 = *(const float4*)&s_fc[v*FP + t0 + 4];
                float cv = cmv[v];
                acc[0] = fmaf(cv, f0.x, acc[0]);
                acc[1] = fmaf(cv, f0.y, acc[1]);
                acc[2] = fmaf(cv, f0.z, acc[2]);
                acc[3] = fmaf(cv, f0.w, acc[3]);
                acc[4] = fmaf(cv, f1.x, acc[4]);
                acc[5] = fmaf(cv, f1.y, acc[5]);
                acc[6] = fmaf(cv, f1.z, acc[6]);
                acc[7] = fmaf(cv, f1.w, acc[7]);
            }
            size_t row = (size_t)((bl*25 + ii)*100 + c);
            size_t gbase = row*NL + t_base + t0;
            unsigned p0 = pack2bf(acc[0], acc[1]);
            unsigned p1 = pack2bf(acc[2], acc[3]);
            if (t0 + 8 <= TH) {
                unsigned p2 = pack2bf(acc[4], acc[5]);
                unsigned p3 = pack2bf(acc[6], acc[7]);
                *reinterpret_cast<uint2*>(pbuf + gbase)     = make_uint2(p0, p1);
                *reinterpret_cast<uint2*>(pbuf + gbase + 4) = make_uint2(p2, p3);
            } else {
                // tail (only h=0, tq=18: 4 valid t's)
                *reinterpret_cast<uint2*>(pbuf + gbase) = make_uint2(p0, p1);
            }
        }
        __syncthreads();
    }
}

// ---------------- group MLP f0/f1/f2 + loss (balanced, reg-resident) -------
// block = (g, chunk of 256 (bl,t)-tasks); tasks per g = nb*292.
__global__ __launch_bounds__(256, 1) void k_mlp(
        const __hip_bfloat16* __restrict__ pbuf,
        const float* __restrict__ f0w, const float* __restrict__ f0b,
        const float* __restrict__ f1w, const float* __restrict__ f1b,
        const float* __restrict__ f2w, const float* __restrict__ f2b,
        float* __restrict__ ws, int b_base, int nb, int nchunks) {
    __shared__ float s_w1t[1000];   // [o][o2]
    __shared__ float s_loss;
    int tid = threadIdx.x;
    int g     = blockIdx.x / nchunks;
    int chunk = blockIdx.x - g*nchunks;
    for (int i = tid; i < 1000; i += 256) {
        int o = i / 10, o2 = i - o*10;
        s_w1t[i] = f1w[g*1000 + o2*100 + o];
    }
    if (tid == 0) s_loss = 0.f;
    __syncthreads();

    const float* w0 = f0w + g*10000;
    const float* b0 = f0b + g*100;
    const float* b1 = f1b + g*10;
    const float* w2 = f2w + g*10;
    float b2 = f2b[g];

    float local = 0.f;
    int tau = chunk*256 + tid;
    if (tau < nb*292) {
        int bl = tau / 292, t = tau - bl*292;
        const __hip_bfloat16* pg = pbuf + ((size_t)(bl*25 + g))*100*NL + t;
        float pr[100];
        #pragma unroll
        for (int cc = 0; cc < 100; cc++) pr[cc] = __bfloat162float(pg[(size_t)cc*NL]);
        float acc2[10];
        #pragma unroll
        for (int o2 = 0; o2 < 10; o2++) acc2[o2] = b1[o2];
        for (int o = 0; o < 100; o += 2) {
            float a  = b0[o];
            float aa = b0[o+1];
            const float* wr  = w0 + o*100;
            const float* wr2 = wr + 100;
            #pragma unroll
            for (int cc = 0; cc < 100; cc++) {
                a  = fmaf(wr[cc],  pr[cc], a);
                aa = fmaf(wr2[cc], pr[cc], aa);
            }
            a  = fmaxf(a, 0.f);
            aa = fmaxf(aa, 0.f);
            #pragma unroll
            for (int o2 = 0; o2 < 10; o2++) {
                acc2[o2] = fmaf(s_w1t[o*10 + o2],     a,  acc2[o2]);
                acc2[o2] = fmaf(s_w1t[(o+1)*10 + o2], aa, acc2[o2]);
            }
        }
        float z3 = b2;
        #pragma unroll
        for (int o2 = 0; o2 < 10; o2++) z3 += w2[o2]*fmaxf(acc2[o2], 0.f);
        z3 = fmaxf(z3, 0.f);
        if (t < NL-1) {
            int b = b_base + bl;
            float d = ws[WS_XS + ((size_t)(b*25 + g))*NT + t + NTL] - z3;
            local = d*d;
        }
    }
    local = waveRed(local);
    if ((tid & 63) == 0) atomicAdd(&s_loss, local);
    __syncthreads();
    if (tid == 0) atomicAdd(&ws[WS_LOSS], s_loss);
}

// ---------------- final scalars ----------------
__global__ void k_final(float* __restrict__ out, const float* __restrict__ ws) {
    out[40000] = ws[WS_LOSS] * (1.f / 465600.f);
    out[40001] = 1e-4f * ws[WS_PAN];
    out[40002] = 1e-4f * ws[WS_REG];
}

extern "C" void kernel_launch(void* const* d_in, const int* in_sizes, int n_in,
                              void* d_out, int out_size, void* d_ws, size_t ws_size,
                              hipStream_t stream) {
    const float* x      = (const float*)d_in[0];
    const float* weight = (const float*)d_in[1];
    const float* wnorm  = (const float*)d_in[2];
    const float* fb0_w  = (const float*)d_in[3];
    const float* fb0_b  = (const float*)d_in[4];
    const float* bn0_g  = (const float*)d_in[5];
    const float* bn0_b  = (const float*)d_in[6];
    const float* fb1_w  = (const float*)d_in[7];
    const float* fb1_b  = (const float*)d_in[8];
    const float* bn1_g  = (const float*)d_in[9];
    const float* bn1_b  = (const float*)d_in[10];
    const float* fb2_w  = (const float*)d_in[11];
    const float* fb2_b  = (const float*)d_in[12];
    const float* bn2_g  = (const float*)d_in[13];
    const float* bn2_b  = (const float*)d_in[14];
    const float* c1_w   = (const float*)d_in[15];
    const float* c1_b   = (const float*)d_in[16];
    const float* c2_w   = (const float*)d_in[17];
    const float* c2_b   = (const float*)d_in[18];
    const float* f0_w   = (const float*)d_in[19];
    const float* f0_b   = (const float*)d_in[20];
    const float* f1_w   = (const float*)d_in[21];
    const float* f1_b   = (const float*)d_in[22];
    const float* f2_w   = (const float*)d_in[23];
    const float* f2_b   = (const float*)d_in[24];

    float* ws  = (float*)d_ws;
    float* out = (float*)d_out;
    __hip_bfloat16* pbuf = (__hip_bfloat16*)(ws + WS_P);

    // zero accumulators (floats 0..255; covers XA + scalar lines)
    hipMemsetAsync(d_ws, 0, 1024, stream);

    k_xstats<<<128, 256, 0, stream>>>(x, ws);
    k_prepw<<<10, 256, 0, stream>>>(weight, ws);
    k_prepw1t<<<32, 256, 0, stream>>>(fb1_w, ws);
    k_prep0<<<1, 64, 0, stream>>>(fb0_w, fb0_b, bn0_g, bn0_b, ws);
    k_zpass<0><<<ZP_BLOCKS, 256, 0, stream>>>(x, fb1_b, fb2_w, fb2_b, ws);
    k_z1red<<<128, 256, 0, stream>>>(bn1_g, bn1_b, ws);
    k_zpass<1><<<ZP_BLOCKS, 256, 0, stream>>>(x, fb1_b, fb2_w, fb2_b, ws);
    k_prep2<<<1, 1, 0, stream>>>(bn2_g, bn2_b, ws);
    k_xs<<<1600, 128, 0, stream>>>(ws);
    k_cm<<<6400, 256, 0, stream>>>(c1_w, c1_b, c2_w, c2_b, ws);
    k_gcs<<<157, 256, 0, stream>>>(ws, out);
    k_pan<<<64, 256, 0, stream>>>(ws);
    k_reg<<<256, 256, 0, stream>>>(f0_w, f1_w, f2_w, ws);

    // Adaptive b-chunking for the bf16 p buffer (deterministic in ws_size ->
    // identical work every call; graph-capture safe).
    const size_t p_bytes_per_b = (size_t)25*100*NL*sizeof(__hip_bfloat16); // 1.46 MB
    size_t fixed_bytes = (size_t)WS_P * sizeof(float);
    size_t avail = ws_size > fixed_bytes ? ws_size - fixed_bytes : 0;
    int bs = (int)(avail / p_bytes_per_b);
    if (bs > 64) bs = 64;
    if (bs < 1)  bs = 1;
    for (int b0 = 0; b0 < 64; b0 += bs) {
        int nb = (64 - b0) < bs ? (64 - b0) : bs;
        k_fcp<<<nb*100, 256, 0, stream>>>(weight, wnorm, pbuf, ws, b0);
        int nch = (nb*292 + 255) / 256;
        k_mlp<<<25*nch, 256, 0, stream>>>(pbuf, f0_w, f0_b, f1_w, f1_b,
                                          f2_w, f2_b, ws, b0, nb, nch);
    }
    k_final<<<1, 1, 0, stream>>>(out, ws);
}

// Round 10
// 754.866 us; speedup vs baseline: 1.8060x; 1.0243x over previous
//
#include <hip/hip_runtime.h>
#include <hip/hip_bf16.h>
#include <string.h>

// Problem constants
#define N_POS 480000      // B*T*V = 64*300*25
#define NB    64
#define NT    300
#define NV    25
#define NCC   100
#define NTL   9
#define NL    292         // T - TL + 1

// Workspace float offsets. Atomic targets live on PRIVATE 64B cache lines
// (stride-16 floats) -- same-line atomic RMWs serialize at ~31cyc/op (R7).
#define WS_XA     0       // 9 accumulators at stride 16 (0,16,...,128)
#define WS_Z2SUM  144
#define WS_Z2SQ   160
#define WS_LOSS   176
#define WS_PAN    192
#define WS_REG    208
#define WS_SC1    224     // 128
#define WS_SH1    352     // 128
#define WS_SC2    480
#define WS_SH2    481
#define WS_WA     512     // 256: packed (sc*w0, sc*w1, sc*w2, ba) per ch
#define WS_W1T    768     // 8192: W1 transposed [c][o]
#define WS_SW     8960    // 2500 = sum_l weight^2 (100x25)
#define WS_HM     11460   // 1600 (B*V t-means)
#define WS_Z1P    13060   // 500*128 z1 sum partials
#define WS_Z1PQ   77060   // 500*128 z1 sumsq partials
#define WS_Z2     141060  // 480000 (b,t,v)
#define WS_XS     621060  // 480000 (b,v,t)
#define WS_CM     1101060 // 4,000,000 (b,c,i,j)
#define WS_P      5101060 // fp32 p buffer starts here (R9: bf16->f32, kills
                          // per-use cvt in k_mlp; compiler kept p packed bf16)

__device__ __forceinline__ float waveRed(float v) {
    #pragma unroll
    for (int off = 32; off > 0; off >>= 1) v += __shfl_down(v, off);
    return v;
}

// ---------------- Pass A: x channel stats (float4, block-reduced) ----------
__global__ __launch_bounds__(256) void k_xstats(const float* __restrict__ x,
                                                float* __restrict__ ws) {
    __shared__ float s_red[4][9];
    int tid = blockIdx.x * 256 + threadIdx.x;
    int nth = gridDim.x * 256;
    float a[9];
    #pragma unroll
    for (int i = 0; i < 9; i++) a[i] = 0.f;
    // 120000 tasks = 64 b * 1875 float4-quads per channel row
    for (int task = tid; task < 120000; task += nth) {
        int b = task / 1875; int q = task - b*1875;
        const float* xb = x + b*22500 + q*4;
        float4 v0 = *(const float4*)(xb);
        float4 v1 = *(const float4*)(xb + 7500);
        float4 v2 = *(const float4*)(xb + 15000);
        const float* p0 = (const float*)&v0;
        const float* p1 = (const float*)&v1;
        const float* p2 = (const float*)&v2;
        #pragma unroll
        for (int k = 0; k < 4; k++) {
            float x0 = p0[k], x1 = p1[k], x2 = p2[k];
            a[0] += x0; a[1] += x1; a[2] += x2;
            a[3] = fmaf(x0,x0,a[3]); a[4] = fmaf(x0,x1,a[4]); a[5] = fmaf(x0,x2,a[5]);
            a[6] = fmaf(x1,x1,a[6]); a[7] = fmaf(x1,x2,a[7]); a[8] = fmaf(x2,x2,a[8]);
        }
    }
    #pragma unroll
    for (int i = 0; i < 9; i++) a[i] = waveRed(a[i]);
    int w = threadIdx.x >> 6;
    if ((threadIdx.x & 63) == 0) {
        #pragma unroll
        for (int i = 0; i < 9; i++) s_red[w][i] = a[i];
    }
    __syncthreads();
    if (threadIdx.x < 9) {
        float s = s_red[0][threadIdx.x] + s_red[1][threadIdx.x]
                + s_red[2][threadIdx.x] + s_red[3][threadIdx.x];
        atomicAdd(&ws[WS_XA + threadIdx.x*16], s);
    }
}

// ---------------- sw[c,m] = sum_l weight^2 ----------------
__global__ void k_prepw(const float* __restrict__ weight, float* __restrict__ ws) {
    int idx = blockIdx.x * blockDim.x + threadIdx.x;
    if (idx < 2500) {
        float s = 0;
        #pragma unroll
        for (int l = 0; l < NTL; l++) { float w = weight[idx*NTL + l]; s += w*w; }
        ws[WS_SW + idx] = s;
    }
}

// ---------------- W1 transpose: W1T[c][o] = w1[o][c] ----------------
__global__ void k_prepw1t(const float* __restrict__ w1g, float* __restrict__ ws) {
    int idx = blockIdx.x * 256 + threadIdx.x;
    if (idx < 8192) {
        int c = idx >> 7, o = idx & 127;
        ws[WS_W1T + idx] = w1g[o*64 + c];
    }
}

// ---------------- BN0 folded affine from x moments (exact linearity) -------
__global__ void k_prep0(const float* __restrict__ w, const float* __restrict__ bb,
                        const float* __restrict__ g, const float* __restrict__ bt,
                        float* __restrict__ ws) {
    int o = threadIdx.x; // 64
    float inv = 1.0f / (float)N_POS;
    float mx0 = ws[WS_XA+0]*inv, mx1 = ws[WS_XA+16]*inv, mx2 = ws[WS_XA+32]*inv;
    float C00 = ws[WS_XA+48]*inv  - mx0*mx0;
    float C01 = ws[WS_XA+64]*inv  - mx0*mx1;
    float C02 = ws[WS_XA+80]*inv  - mx0*mx2;
    float C11 = ws[WS_XA+96]*inv  - mx1*mx1;
    float C12 = ws[WS_XA+112]*inv - mx1*mx2;
    float C22 = ws[WS_XA+128]*inv - mx2*mx2;
    float w0 = w[o*3], w1 = w[o*3+1], w2 = w[o*3+2];
    float mu  = w0*mx0 + w1*mx1 + w2*mx2 + bb[o];
    float var = w0*w0*C00 + w1*w1*C11 + w2*w2*C22
              + 2.f*(w0*w1*C01 + w0*w2*C02 + w1*w2*C12);
    float sc = g[o] / sqrtf(var + 1e-5f);
    float sh = bt[o] - sc*mu;
    ws[WS_WA + o*4 + 0] = sc*w0;
    ws[WS_WA + o*4 + 1] = sc*w1;
    ws[WS_WA + o*4 + 2] = sc*w2;
    ws[WS_WA + o*4 + 3] = sc*bb[o] + sh;
}

// ---------------- z1 GEMM pass (LDS-tiled, 4pos x 8out register tiles) ----
#define ZP_BLOCKS 500
#define ZP_CHUNKS 15
template<int MODE>
__global__ __launch_bounds__(256) void k_zpass(
        const float* __restrict__ x,
        const float* __restrict__ b1g,
        const float* __restrict__ w2g,
        const float* __restrict__ b2g,
        float* __restrict__ ws) {
    __shared__ float smem[12544];         // 50176 B
    float* s_h0  = smem;                  // [64 ch][68 pos-pad]
    float* s_w1t = smem + 4352;           // [64 c][128 o]
    int tid = threadIdx.x;

    for (int i = tid; i < 8192; i += 256) s_w1t[i] = ws[WS_W1T + i];

    int pos = tid & 63, cset = tid >> 6;  // staging mapping
    int pg  = tid >> 4, og  = tid & 15;   // GEMM mapping

    float b1r[8];
    #pragma unroll
    for (int o = 0; o < 8; o++) b1r[o] = b1g[og*8 + o];
    float sc1r[8], sh1r[8], w2r[8], b2v = 0.f;
    if constexpr (MODE == 1) {
        #pragma unroll
        for (int o = 0; o < 8; o++) {
            sc1r[o] = ws[WS_SC1 + og*8 + o];
            sh1r[o] = ws[WS_SH1 + og*8 + o];
            w2r[o]  = w2g[og*8 + o];
        }
        b2v = b2g[0];
    }
    float zs[8], zq[8];
    #pragma unroll
    for (int o = 0; o < 8; o++) { zs[o] = 0.f; zq[o] = 0.f; }
    float z2s = 0.f, z2q = 0.f;

    __syncthreads();

    for (int ci = 0; ci < ZP_CHUNKS; ci++) {
        int chunk = blockIdx.x * ZP_CHUNKS + ci;
        int P = chunk*64 + pos;
        int b = P / 7500, rem = P - b*7500;
        const float* xb = x + b*22500 + rem;
        float x0 = xb[0], x1 = xb[7500], x2 = xb[15000];
        #pragma unroll
        for (int k = 0; k < 16; k++) {
            int ch = cset*16 + k;
            const float4 wa = *(const float4*)&ws[WS_WA + ch*4];
            s_h0[ch*68 + pos] = fmaxf(wa.x*x0 + wa.y*x1 + wa.z*x2 + wa.w, 0.f);
        }
        __syncthreads();

        float acc[4][8];
        #pragma unroll
        for (int p = 0; p < 4; p++)
            #pragma unroll
            for (int o = 0; o < 8; o++) acc[p][o] = 0.f;

        #pragma unroll 4
        for (int c = 0; c < 64; c++) {
            float4 ha = *(const float4*)&s_h0[c*68 + 4*pg];
            float4 wl = *(const float4*)&s_w1t[c*128 + 8*og];
            float4 wh = *(const float4*)&s_w1t[c*128 + 8*og + 4];
            #pragma unroll
            for (int p = 0; p < 4; p++) {
                float hv = ((const float*)&ha)[p];
                #pragma unroll
                for (int o = 0; o < 4; o++) {
                    acc[p][o]   = fmaf(hv, ((const float*)&wl)[o], acc[p][o]);
                    acc[p][o+4] = fmaf(hv, ((const float*)&wh)[o], acc[p][o+4]);
                }
            }
        }

        if constexpr (MODE == 0) {
            #pragma unroll
            for (int o = 0; o < 8; o++) {
                #pragma unroll
                for (int p = 0; p < 4; p++) {
                    float z = acc[p][o] + b1r[o];
                    zs[o] += z; zq[o] += z*z;
                }
            }
            __syncthreads();   // protect s_h0 before next staging
        } else {
            float zp[4];
            #pragma unroll
            for (int p = 0; p < 4; p++) {
                float s = 0.f;
                #pragma unroll
                for (int o = 0; o < 8; o++) {
                    float z = acc[p][o] + b1r[o];
                    s += w2r[o]*fmaxf(sc1r[o]*z + sh1r[o], 0.f);
                }
                zp[p] = s;
            }
            __syncthreads();               // all GEMM reads of s_h0 done
            float* s_z2p = smem;           // [64 pos][17]
            #pragma unroll
            for (int p = 0; p < 4; p++) s_z2p[(4*pg + p)*17 + og] = zp[p];
            __syncthreads();
            if (tid < 64) {
                float z2 = b2v;
                #pragma unroll
                for (int j = 0; j < 16; j++) z2 += s_z2p[tid*17 + j];
                ws[WS_Z2 + chunk*64 + tid] = z2;
                z2s += z2; z2q += z2*z2;
            }
            __syncthreads();               // protect overlay before next staging
        }
    }

    if constexpr (MODE == 0) {
        // block partials -> global arrays (NO atomics; reduced by k_z1red)
        float* s_part = smem;              // [128 o][17]
        #pragma unroll
        for (int o = 0; o < 8; o++) s_part[(og*8 + o)*17 + pg] = zs[o];
        __syncthreads();
        if (tid < 128) {
            float s = 0.f;
            #pragma unroll
            for (int j = 0; j < 16; j++) s += s_part[tid*17 + j];
            ws[WS_Z1P + blockIdx.x*128 + tid] = s;
        }
        __syncthreads();
        #pragma unroll
        for (int o = 0; o < 8; o++) s_part[(og*8 + o)*17 + pg] = zq[o];
        __syncthreads();
        if (tid < 128) {
            float s = 0.f;
            #pragma unroll
            for (int j = 0; j < 16; j++) s += s_part[tid*17 + j];
            ws[WS_Z1PQ + blockIdx.x*128 + tid] = s;
        }
    } else {
        if (tid < 64) {
            z2s = waveRed(z2s);
            z2q = waveRed(z2q);
            if (tid == 0) { atomicAdd(&ws[WS_Z2SUM], z2s); atomicAdd(&ws[WS_Z2SQ], z2q); }
        }
    }
}

// ---------------- reduce z1 partials -> BN1 affine ----------
__global__ __launch_bounds__(256) void k_z1red(const float* __restrict__ g,
                                               const float* __restrict__ bt,
                                               float* __restrict__ ws) {
    __shared__ float ss[4], qq[4];
    int o = blockIdx.x;  // 0..127
    float s = 0.f, q = 0.f;
    for (int blk = threadIdx.x; blk < ZP_BLOCKS; blk += 256) {
        s += ws[WS_Z1P  + blk*128 + o];
        q += ws[WS_Z1PQ + blk*128 + o];
    }
    s = waveRed(s); q = waveRed(q);
    int w = threadIdx.x >> 6;
    if ((threadIdx.x & 63) == 0) { ss[w] = s; qq[w] = q; }
    __syncthreads();
    if (threadIdx.x == 0) {
        float S = ss[0]+ss[1]+ss[2]+ss[3];
        float Q = qq[0]+qq[1]+qq[2]+qq[3];
        float inv = 1.0f / (float)N_POS;
        float m = S*inv;
        float v = Q*inv - m*m;
        float sc = g[o] / sqrtf(v + 1e-5f);
        ws[WS_SC1+o] = sc;
        ws[WS_SH1+o] = bt[o] - sc*m;
    }
}

__global__ void k_prep2(const float* __restrict__ g, const float* __restrict__ bt,
                        float* __restrict__ ws) {
    float inv = 1.0f / (float)N_POS;
    float m = ws[WS_Z2SUM]*inv;
    float v = ws[WS_Z2SQ]*inv - m*m;
    float sc = g[0] / sqrtf(v + 1e-5f);
    ws[WS_SC2] = sc;
    ws[WS_SH2] = bt[0] - sc*m;
}

// ---------------- x_series (b,v,t) + per-(b,v) t-mean ----------------
__global__ void k_xs(float* __restrict__ ws) {
    __shared__ float red[128];
    int bid = blockIdx.x;       // b*25+v
    int b = bid / 25, v = bid - b*25;
    float sc = ws[WS_SC2], sh = ws[WS_SH2];
    float local = 0.f;
    for (int t = threadIdx.x; t < NT; t += 128) {
        float val = fmaxf(sc * ws[WS_Z2 + b*7500 + t*25 + v] + sh, 0.f);
        ws[WS_XS + (size_t)bid*NT + t] = val;
        local += val;
    }
    red[threadIdx.x] = local;
    __syncthreads();
    for (int s = 64; s > 0; s >>= 1) {
        if (threadIdx.x < s) red[threadIdx.x] += red[threadIdx.x + s];
        __syncthreads();
    }
    if (threadIdx.x == 0) ws[WS_HM + bid] = red[0] * (1.f/300.f);
}

// ---------------- cm[b,c,i,j] = tanh(x1[b,c,i]-x2[b,c,j]) ----------------
__global__ void k_cm(const float* __restrict__ c1w, const float* __restrict__ c1b,
                     const float* __restrict__ c2w, const float* __restrict__ c2b,
                     float* __restrict__ ws) {
    __shared__ float s_hm[25];
    int bid = blockIdx.x;       // b*100+c
    int b = bid / 100, c = bid - b*100;
    if (threadIdx.x < 25) s_hm[threadIdx.x] = ws[WS_HM + b*25 + threadIdx.x];
    float a1 = c1w[c], d1 = c1b[c], a2 = c2w[c], d2 = c2b[c];
    __syncthreads();
    for (int idx = threadIdx.x; idx < 625; idx += 256) {
        int i = idx / 25, j = idx - i*25;
        ws[WS_CM + (size_t)bid*625 + idx] = tanhf(a1*s_hm[i] + d1 - a2*s_hm[j] - d2);
    }
}

// ---------------- GCs ----------------
__global__ void k_gcs(const float* __restrict__ ws, float* __restrict__ out) {
    int gid = blockIdx.x * 256 + threadIdx.x;
    if (gid < 40000) {
        int b = gid / 625; int rem = gid - b*625; int m = rem % 25;
        float acc = 0.f;
        for (int c = 0; c < 100; c++) {
            float v = ws[WS_CM + ((size_t)(b*100+c))*625 + rem];
            acc += v*v*ws[WS_SW + c*25 + m];
        }
        out[gid] = sqrtf(acc);
    }
}

// ---------------- panelty ----------------
__global__ void k_pan(float* __restrict__ ws) {
    __shared__ float s_colsq[25];
    __shared__ float s_n1, s_r;
    int tid = threadIdx.x;
    int b = blockIdx.x;
    if (tid < 25) s_colsq[tid] = 0.f;
    if (tid == 0) { s_n1 = 0.f; s_r = 0.f; }
    __syncthreads();
    float ln1 = 0.f;
    for (int idx = tid; idx < 625; idx += 256) {
        int j = idx % 25;
        float sq = 0.f;
        for (int c = 0; c < 100; c++) {
            float v = ws[WS_CM + ((size_t)(b*100+c))*625 + idx];
            sq += v*v;
        }
        ln1 += sqrtf(sq);
        atomicAdd(&s_colsq[j], sq);
    }
    ln1 = waveRed(ln1);
    if ((tid & 63) == 0) atomicAdd(&s_n1, ln1);
    __syncthreads();
    if (tid < 25) atomicAdd(&s_r, sqrtf(s_colsq[tid]));
    __syncthreads();
    if (tid == 0) atomicAdd(&ws[WS_PAN], s_n1 + s_r);
}

// ---------------- regularize ----------------
__global__ void k_reg(const float* __restrict__ f0w, const float* __restrict__ f1w,
                      const float* __restrict__ f2w, float* __restrict__ ws) {
    __shared__ float sred[4];
    int tid = blockIdx.x * blockDim.x + threadIdx.x;
    int nth = gridDim.x * blockDim.x;
    float a = 0.f;
    for (int i = tid; i < 275250; i += nth) {
        float w;
        if (i < 250000) w = f0w[i];
        else if (i < 275000) w = f1w[i - 250000];
        else w = f2w[i - 275000];
        a += w*w;
    }
    a = waveRed(a);
    int w = threadIdx.x >> 6;
    if ((threadIdx.x & 63) == 0) sred[w] = a;
    __syncthreads();
    if (threadIdx.x == 0)
        atomicAdd(&ws[WS_REG], sred[0]+sred[1]+sred[2]+sred[3]);
}

// ---------------- Fc + p per (b,c), register-tiled, t-split halves ----------
// half 0: t in [0,148); half 1: t in [148,292) (len 144)
#define XP 156   // xs row pad (needs up to 156 elems)
#define FP 152   // fc row pad (tail b128 reads up to idx 151)
__global__ __launch_bounds__(256) void k_fcp(
        const float* __restrict__ weight, const float* __restrict__ wnorm,
        float* __restrict__ pbuf, const float* __restrict__ ws, int b_base) {
    __shared__ float s_xs[25*XP];   // 3900
    __shared__ float s_fc[25*FP];   // 3800
    __shared__ float s_wn[225];
    __shared__ float s_cm[625];
    int tid = threadIdx.x;
    int bid = blockIdx.x;
    int bl = bid / 100, c = bid - bl*100;
    int b = b_base + bl;

    for (int i = tid; i < 225; i += 256) s_wn[i] = weight[c*225 + i] / wnorm[i];
    for (int i = tid; i < 625; i += 256) s_cm[i] = ws[WS_CM + ((size_t)(b*100+c))*625 + i];

    #pragma unroll
    for (int h = 0; h < 2; h++) {
        const int t_base = h ? 148 : 0;
        const int TH     = h ? 144 : 148;   // half length
        const int NTQ4   = TH / 4;          // fc tiles per row (37 / 36, exact)
        const int NPV    = ((TH + 7) / 8);  // pv t-tiles (19 / 18)

        // stage xs rows [v][0..TH+8)
        for (int i = tid; i < 25*XP; i += 256) {
            int v = i / XP, u = i - v*XP;
            if (u < TH + 8) s_xs[i] = ws[WS_XS + (size_t)(b*25+v)*NT + t_base + u];
        }
        __syncthreads();

        // fc: task = v*NTQ4 + tq, 4 t's per task
        for (int task = tid; task < 25*NTQ4; task += 256) {
            int v = task / NTQ4, tq = task - v*NTQ4;
            int t0 = tq*4;
            float4 xa = *(const float4*)&s_xs[v*XP + t0];
            float4 xb = *(const float4*)&s_xs[v*XP + t0 + 4];
            float4 xc = *(const float4*)&s_xs[v*XP + t0 + 8];
            float xr[12];
            xr[0]=xa.x; xr[1]=xa.y; xr[2]=xa.z; xr[3]=xa.w;
            xr[4]=xb.x; xr[5]=xb.y; xr[6]=xb.z; xr[7]=xb.w;
            xr[8]=xc.x; xr[9]=xc.y; xr[10]=xc.z; xr[11]=xc.w;
            float f[4];
            #pragma unroll
            for (int k = 0; k < 4; k++) f[k] = 0.f;
            #pragma unroll
            for (int l = 0; l < NTL; l++) {
                float w = s_wn[v*NTL + l];
                #pragma unroll
                for (int k = 0; k < 4; k++) f[k] = fmaf(xr[k + l], w, f[k]);
            }
            *(float4*)&s_fc[v*FP + t0] = make_float4(f[0], f[1], f[2], f[3]);
        }
        __syncthreads();

        // PV: task = tq*25 + ii, 8 t's per task
        for (int task = tid; task < NPV*25; task += 256) {
            int tq = task / 25, ii = task - tq*25;
            int t0 = tq*8;
            float cmv[25];
            #pragma unroll
            for (int v = 0; v < 25; v++) cmv[v] = s_cm[v*25 + ii];
            float acc[8];
            #pragma unroll
            for (int k = 0; k < 8; k++) acc[k] = 0.f;
            #pragma unroll
            for (int v = 0; v < 25; v++) {
                float4 f0 = *(const float4*)&s_fc[v*FP + t0];
                float4 f1 = *(const float4*)&s_fc[v*FP + t0 + 4];
                float cv = cmv[v];
                acc[0] = fmaf(cv, f0.x, acc[0]);
                acc[1] = fmaf(cv, f0.y, acc[1]);
                acc[2] = fmaf(cv, f0.z, acc[2]);
                acc[3] = fmaf(cv, f0.w, acc[3]);
                acc[4] = fmaf(cv, f1.x, acc[4]);
                acc[5] = fmaf(cv, f1.y, acc[5]);
                acc[6] = fmaf(cv, f1.z, acc[6]);
                acc[7] = fmaf(cv, f1.w, acc[7]);
            }
            size_t row = (size_t)((bl*25 + ii)*100 + c);
            size_t gbase = row*NL + t_base + t0;
            // fp32 stores; 292%4==0 and 148%4==0 keep these 16B-aligned
            *(float4*)(pbuf + gbase) = make_float4(acc[0], acc[1], acc[2], acc[3]);
            if (t0 + 8 <= TH)
                *(float4*)(pbuf + gbase + 4) = make_float4(acc[4], acc[5], acc[6], acc[7]);
        }
        __syncthreads();
    }
}

// ---------------- group MLP f0/f1/f2 + loss (balanced, reg-resident) -------
// block = (g, chunk of 256 (bl,t)-tasks); tasks per g = nb*292.
__global__ __launch_bounds__(256, 1) void k_mlp(
        const float* __restrict__ pbuf,
        const float* __restrict__ f0w, const float* __restrict__ f0b,
        const float* __restrict__ f1w, const float* __restrict__ f1b,
        const float* __restrict__ f2w, const float* __restrict__ f2b,
        float* __restrict__ ws, int b_base, int nb, int nchunks) {
    __shared__ float s_w1t[1000];   // [o][o2]
    __shared__ float s_loss;
    int tid = threadIdx.x;
    int g     = blockIdx.x / nchunks;
    int chunk = blockIdx.x - g*nchunks;
    for (int i = tid; i < 1000; i += 256) {
        int o = i / 10, o2 = i - o*10;
        s_w1t[i] = f1w[g*1000 + o2*100 + o];
    }
    if (tid == 0) s_loss = 0.f;
    __syncthreads();

    const float* w0 = f0w + g*10000;
    const float* b0 = f0b + g*100;
    const float* b1 = f1b + g*10;
    const float* w2 = f2w + g*10;
    float b2 = f2b[g];

    float local = 0.f;
    int tau = chunk*256 + tid;
    if (tau < nb*292) {
        int bl = tau / 292, t = tau - bl*292;
        const float* pg = pbuf + ((size_t)(bl*25 + g))*100*NL + t;
        float pr[100];
        #pragma unroll
        for (int cc = 0; cc < 100; cc++) pr[cc] = pg[(size_t)cc*NL];
        float acc2[10];
        #pragma unroll
        for (int o2 = 0; o2 < 10; o2++) acc2[o2] = b1[o2];
        for (int o = 0; o < 100; o += 2) {
            float a  = b0[o];
            float aa = b0[o+1];
            const float* wr  = w0 + o*100;
            const float* wr2 = wr + 100;
            #pragma unroll
            for (int cc = 0; cc < 100; cc++) {
                a  = fmaf(wr[cc],  pr[cc], a);
                aa = fmaf(wr2[cc], pr[cc], aa);
            }
            a  = fmaxf(a, 0.f);
            aa = fmaxf(aa, 0.f);
            #pragma unroll
            for (int o2 = 0; o2 < 10; o2++) {
                acc2[o2] = fmaf(s_w1t[o*10 + o2],     a,  acc2[o2]);
                acc2[o2] = fmaf(s_w1t[(o+1)*10 + o2], aa, acc2[o2]);
            }
        }
        float z3 = b2;
        #pragma unroll
        for (int o2 = 0; o2 < 10; o2++) z3 += w2[o2]*fmaxf(acc2[o2], 0.f);
        z3 = fmaxf(z3, 0.f);
        if (t < NL-1) {
            int b = b_base + bl;
            float d = ws[WS_XS + ((size_t)(b*25 + g))*NT + t + NTL] - z3;
            local = d*d;
        }
    }
    local = waveRed(local);
    if ((tid & 63) == 0) atomicAdd(&s_loss, local);
    __syncthreads();
    if (tid == 0) atomicAdd(&ws[WS_LOSS], s_loss);
}

// ---------------- final scalars ----------------
__global__ void k_final(float* __restrict__ out, const float* __restrict__ ws) {
    out[40000] = ws[WS_LOSS] * (1.f / 465600.f);
    out[40001] = 1e-4f * ws[WS_PAN];
    out[40002] = 1e-4f * ws[WS_REG];
}

extern "C" void kernel_launch(void* const* d_in, const int* in_sizes, int n_in,
                              void* d_out, int out_size, void* d_ws, size_t ws_size,
                              hipStream_t stream) {
    const float* x      = (const float*)d_in[0];
    const float* weight = (const float*)d_in[1];
    const float* wnorm  = (const float*)d_in[2];
    const float* fb0_w  = (const float*)d_in[3];
    const float* fb0_b  = (const float*)d_in[4];
    const float* bn0_g  = (const float*)d_in[5];
    const float* bn0_b  = (const float*)d_in[6];
    const float* fb1_w  = (const float*)d_in[7];
    const float* fb1_b  = (const float*)d_in[8];
    const float* bn1_g  = (const float*)d_in[9];
    const float* bn1_b  = (const float*)d_in[10];
    const float* fb2_w  = (const float*)d_in[11];
    const float* fb2_b  = (const float*)d_in[12];
    const float* bn2_g  = (const float*)d_in[13];
    const float* bn2_b  = (const float*)d_in[14];
    const float* c1_w   = (const float*)d_in[15];
    const float* c1_b   = (const float*)d_in[16];
    const float* c2_w   = (const float*)d_in[17];
    const float* c2_b   = (const float*)d_in[18];
    const float* f0_w   = (const float*)d_in[19];
    const float* f0_b   = (const float*)d_in[20];
    const float* f1_w   = (const float*)d_in[21];
    const float* f1_b   = (const float*)d_in[22];
    const float* f2_w   = (const float*)d_in[23];
    const float* f2_b   = (const float*)d_in[24];

    float* ws  = (float*)d_ws;
    float* out = (float*)d_out;
    float* pbuf = ws + WS_P;

    // zero accumulators (floats 0..255; covers XA + scalar lines)
    hipMemsetAsync(d_ws, 0, 1024, stream);

    k_xstats<<<128, 256, 0, stream>>>(x, ws);
    k_prepw<<<10, 256, 0, stream>>>(weight, ws);
    k_prepw1t<<<32, 256, 0, stream>>>(fb1_w, ws);
    k_prep0<<<1, 64, 0, stream>>>(fb0_w, fb0_b, bn0_g, bn0_b, ws);
    k_zpass<0><<<ZP_BLOCKS, 256, 0, stream>>>(x, fb1_b, fb2_w, fb2_b, ws);
    k_z1red<<<128, 256, 0, stream>>>(bn1_g, bn1_b, ws);
    k_zpass<1><<<ZP_BLOCKS, 256, 0, stream>>>(x, fb1_b, fb2_w, fb2_b, ws);
    k_prep2<<<1, 1, 0, stream>>>(bn2_g, bn2_b, ws);
    k_xs<<<1600, 128, 0, stream>>>(ws);
    k_cm<<<6400, 256, 0, stream>>>(c1_w, c1_b, c2_w, c2_b, ws);
    k_gcs<<<157, 256, 0, stream>>>(ws, out);
    k_pan<<<64, 256, 0, stream>>>(ws);
    k_reg<<<256, 256, 0, stream>>>(f0_w, f1_w, f2_w, ws);

    // Adaptive b-chunking for the fp32 p buffer (deterministic in ws_size ->
    // identical work every call; graph-capture safe).
    const size_t p_bytes_per_b = (size_t)25*100*NL*sizeof(float); // 2.92 MB
    size_t fixed_bytes = (size_t)WS_P * sizeof(float);
    size_t avail = ws_size > fixed_bytes ? ws_size - fixed_bytes : 0;
    int bs = (int)(avail / p_bytes_per_b);
    if (bs > 64) bs = 64;
    if (bs < 1)  bs = 1;
    for (int b0 = 0; b0 < 64; b0 += bs) {
        int nb = (64 - b0) < bs ? (64 - b0) : bs;
        k_fcp<<<nb*100, 256, 0, stream>>>(weight, wnorm, pbuf, ws, b0);
        int nch = (nb*292 + 255) / 256;
        k_mlp<<<25*nch, 256, 0, stream>>>(pbuf, f0_w, f0_b, f1_w, f1_b,
                                          f2_w, f2_b, ws, b0, nb, nch);
    }
    k_final<<<1, 1, 0, stream>>>(out, ws);
}